// Round 12
// baseline (473.889 us; speedup 1.0000x reference)
//
#include <hip/hip_runtime.h>
#include <hip/hip_bf16.h>
#include <math.h>

#define NB   1024
#define LL   100
#define DD   256
#define DINN 704
#define VV   32000
#define RR   129
#define KAV  512
#define ROWU 129   // enc LDS row stride in dwords (odd => conflict-free)

typedef float f32x4 __attribute__((ext_vector_type(4)));
typedef float f32x2 __attribute__((ext_vector_type(2)));
typedef short s16x8 __attribute__((ext_vector_type(8)));
typedef unsigned short u16;
typedef unsigned int u32;

__device__ __forceinline__ float sigf(float x) { return 1.0f / (1.0f + __expf(-x)); }

__device__ __forceinline__ u16 f2bf(float f) {
    u32 u = __float_as_uint(f);
    u += 0x7fffu + ((u >> 16) & 1u);
    return (u16)(u >> 16);
}
__device__ __forceinline__ float bf2f(u16 s) {
    return __uint_as_float(((u32)s) << 16);
}

// ---------------------------------------------------------------------------
// K-conv: fp32->bf16 conversions (prim_emb, W_ih, W_hh, x, h0) + rule_proj^T.
// ---------------------------------------------------------------------------
__global__ __launch_bounds__(256) void k_conv(
    const float* __restrict__ prim_emb, u16* __restrict__ prim_bf,
    const float* __restrict__ W_ih, u16* __restrict__ wih_bf,
    const float* __restrict__ W_hh, u16* __restrict__ whh_bf,
    const float* __restrict__ x, u16* __restrict__ x_bf,
    const float* __restrict__ h0, u16* __restrict__ h0_bf,
    const float* __restrict__ rule_emb, const float* __restrict__ W_rule_proj,
    float* __restrict__ rpT)
{
    __shared__ float re_s[128];
    const int bx = blockIdx.x, t = threadIdx.x;

    const float* src; u16* dst; int off;
    if (bx < 2000)      { src = prim_emb; dst = prim_bf; off = bx * 2048; }
    else if (bx < 2352) { src = W_ih;  dst = wih_bf; off = (bx - 2000) * 2048; }
    else if (bx < 2480) { src = W_hh;  dst = whh_bf; off = (bx - 2352) * 2048; }
    else if (bx < 2832) { src = x;     dst = x_bf;   off = (bx - 2480) * 2048; }
    else                { src = h0;    dst = h0_bf;  off = (bx - 2832) * 2048; }

    if (bx < RR && t < 128) re_s[t] = rule_emb[bx * 128 + t];

    int i = off + t * 8;
    f32x4 a = *reinterpret_cast<const f32x4*>(&src[i]);
    f32x4 b = *reinterpret_cast<const f32x4*>(&src[i + 4]);
    s16x8 r;
    r[0] = (short)f2bf(a[0]); r[1] = (short)f2bf(a[1]);
    r[2] = (short)f2bf(a[2]); r[3] = (short)f2bf(a[3]);
    r[4] = (short)f2bf(b[0]); r[5] = (short)f2bf(b[1]);
    r[6] = (short)f2bf(b[2]); r[7] = (short)f2bf(b[3]);
    *reinterpret_cast<s16x8*>(&dst[i]) = r;

    if (bx < RR) {
        __syncthreads();
        float acc = 0.f;
        const float* __restrict__ wr = &W_rule_proj[t * 128];
#pragma unroll 8
        for (int k = 0; k < 128; k += 4) {
            f32x4 w4 = *reinterpret_cast<const f32x4*>(&wr[k]);
            acc += w4[0] * re_s[k] + w4[1] * re_s[k + 1]
                 + w4[2] * re_s[k + 2] + w4[3] * re_s[k + 3];
        }
        rpT[t * 192 + bx] = acc;     // transposed [256][192-padded]
    }
}

// ---------------------------------------------------------------------------
// K1: LSTM via bf16 MFMA. (unchanged from R11)
// ---------------------------------------------------------------------------
__global__ __launch_bounds__(256) void k_lstm(
    const u16* __restrict__ x_bf, const u16* __restrict__ h0_bf,
    const float* __restrict__ c0,
    const u16* __restrict__ wih_bf, const u16* __restrict__ whh_bf,
    const float* __restrict__ b_ih, const float* __restrict__ b_hh,
    float* __restrict__ out_h, float* __restrict__ out_c)
{
    const int t = threadIdx.x;
    const int lane = t & 63, w = t >> 6;
    const int lm = lane & 15, lq = lane >> 4;
    const int dg = blockIdx.x;
    const int row0 = blockIdx.y * 128 + w * 32;
    f32x4 acc[4][2] = {};

    for (int kt = 0; kt < 22; ++kt) {
        const int ko = kt * 32 + lq * 8;
        s16x8 bfr[4], afr[2];
#pragma unroll
        for (int mg = 0; mg < 4; ++mg)
            bfr[mg] = *reinterpret_cast<const s16x8*>(
                &wih_bf[(mg * 256 + dg * 16 + lm) * DINN + ko]);
#pragma unroll
        for (int ng = 0; ng < 2; ++ng)
            afr[ng] = *reinterpret_cast<const s16x8*>(
                &x_bf[(row0 + ng * 16 + lm) * DINN + ko]);
#pragma unroll
        for (int mg = 0; mg < 4; ++mg)
#pragma unroll
            for (int ng = 0; ng < 2; ++ng)
                acc[mg][ng] = __builtin_amdgcn_mfma_f32_16x16x32_bf16(
                    bfr[mg], afr[ng], acc[mg][ng], 0, 0, 0);
    }
    for (int kt = 0; kt < 8; ++kt) {
        const int ko = kt * 32 + lq * 8;
        s16x8 bfr[4], afr[2];
#pragma unroll
        for (int mg = 0; mg < 4; ++mg)
            bfr[mg] = *reinterpret_cast<const s16x8*>(
                &whh_bf[(mg * 256 + dg * 16 + lm) * DD + ko]);
#pragma unroll
        for (int ng = 0; ng < 2; ++ng)
            afr[ng] = *reinterpret_cast<const s16x8*>(
                &h0_bf[(row0 + ng * 16 + lm) * DD + ko]);
#pragma unroll
        for (int mg = 0; mg < 4; ++mg)
#pragma unroll
            for (int ng = 0; ng < 2; ++ng)
                acc[mg][ng] = __builtin_amdgcn_mfma_f32_16x16x32_bf16(
                    bfr[mg], afr[ng], acc[mg][ng], 0, 0, 0);
    }

    const int dc = dg * 16 + lq * 4;
    f32x4 bi[4];
#pragma unroll
    for (int mg = 0; mg < 4; ++mg) {
        f32x4 a4 = *reinterpret_cast<const f32x4*>(&b_ih[mg * 256 + dc]);
        f32x4 b4 = *reinterpret_cast<const f32x4*>(&b_hh[mg * 256 + dc]);
        bi[mg][0] = a4[0] + b4[0]; bi[mg][1] = a4[1] + b4[1];
        bi[mg][2] = a4[2] + b4[2]; bi[mg][3] = a4[3] + b4[3];
    }
#pragma unroll
    for (int ng = 0; ng < 2; ++ng) {
        const int row = row0 + ng * 16 + lm;
        f32x4 c4 = *reinterpret_cast<const f32x4*>(&c0[row * DD + dc]);
        f32x4 h4, cc4;
#pragma unroll
        for (int r = 0; r < 4; ++r) {
            float iv = acc[0][ng][r] + bi[0][r];
            float fv = acc[1][ng][r] + bi[1][r];
            float gv = acc[2][ng][r] + bi[2][r];
            float ov = acc[3][ng][r] + bi[3][r];
            float cc = sigf(fv) * c4[r] + sigf(iv) * tanhf(gv);
            cc4[r] = cc;
            h4[r] = sigf(ov) * tanhf(cc);
        }
        *reinterpret_cast<f32x4*>(&out_c[row * DD + dc]) = cc4;
        *reinterpret_cast<f32x4*>(&out_h[row * DD + dc]) = h4;
    }
}

// ---------------------------------------------------------------------------
// K-hw: hW = h @ W_attn  (GEMM, unchanged)
// ---------------------------------------------------------------------------
__global__ __launch_bounds__(256) void k_hw(
    const float* __restrict__ h, const float* __restrict__ W_attn, float* __restrict__ hW)
{
    __shared__ __align__(16) float As[16][36];
    __shared__ __align__(16) float Bs[16][68];
    const int t = threadIdx.x;
    const int row0 = blockIdx.x * 32;
    const int col0 = blockIdx.y * 64;
    const int tr = t >> 4, tc = t & 15;
    float acc[2][4] = {};
    for (int kt = 0; kt < 16; ++kt) {
        __syncthreads();
#pragma unroll
        for (int p = 0; p < 2; ++p) {
            int e = t + p * 256;
            int r = e >> 4, kk = e & 15;
            As[kk][r] = h[(row0 + r) * DD + kt * 16 + kk];
        }
#pragma unroll
        for (int p = 0; p < 4; ++p) {
            int e = t + p * 256;
            int kk = e >> 6, c = e & 63;
            Bs[kk][c] = W_attn[(kt * 16 + kk) * DD + col0 + c];
        }
        __syncthreads();
#pragma unroll
        for (int kk = 0; kk < 16; ++kk) {
            float a0 = As[kk][tr * 2], a1 = As[kk][tr * 2 + 1];
            f32x4 b = *reinterpret_cast<const f32x4*>(&Bs[kk][tc * 4]);
#pragma unroll
            for (int i = 0; i < 4; ++i) {
                acc[0][i] = fmaf(a0, b[i], acc[0][i]);
                acc[1][i] = fmaf(a1, b[i], acc[1][i]);
            }
        }
    }
#pragma unroll
    for (int j = 0; j < 2; ++j) {
        f32x4 v;
#pragma unroll
        for (int i = 0; i < 4; ++i) v[i] = acc[j][i];
        *reinterpret_cast<f32x4*>(&hW[(row0 + tr * 2 + j) * DD + col0 + tc * 4]) = v;
    }
}

// ---------------------------------------------------------------------------
// K-attn2 [AMPLIFIED x reps for diagnostics — body is idempotent]
// ---------------------------------------------------------------------------
__global__ __launch_bounds__(256, 2) void k_attn2(
    const float* __restrict__ src_enc, const float* __restrict__ hW,
    float* __restrict__ ctx_out, int reps)
{
    __shared__ u32 enc_u[LL * ROWU];
    __shared__ __align__(16) float part[4][DD];
    __shared__ __align__(16) float hw_s[DD];
    __shared__ float sc_s[LL];
    __shared__ float al_s[LL];

    const int b = blockIdx.x, t = threadIdx.x;
    const int lane = t & 63, w = t >> 6;
    const float* __restrict__ enc = src_enc + (size_t)b * LL * DD;

    for (int rep = 0; rep < reps; ++rep) {
    hw_s[t] = hW[b * DD + t];

#pragma unroll
    for (int p = 0; p < 25; ++p) {
        int q = p * 256 + t;
        int l = q >> 6, dq = q & 63;
        f32x4 ev = *reinterpret_cast<const f32x4*>(&enc[l * DD + dq * 4]);
        u32 w0 = (u32)f2bf(ev[0]) | ((u32)f2bf(ev[1]) << 16);
        u32 w1 = (u32)f2bf(ev[2]) | ((u32)f2bf(ev[3]) << 16);
        enc_u[l * ROWU + dq * 2]     = w0;
        enc_u[l * ROWU + dq * 2 + 1] = w1;
    }
    __syncthreads();

    // scores: lane-per-l, wave pair splits d
    {
        const int sl = ((w >> 1) << 6) + lane;
        float sp = 0.f;
        if (sl < LL) {
            const u32* __restrict__ rp = enc_u + sl * ROWU + ((w & 1) << 6);
            const float* __restrict__ hp = hw_s + ((w & 1) << 7);
#pragma unroll 32
            for (int k = 0; k < 64; ++k) {
                u32 v = rp[k];
                sp = fmaf(bf2f((u16)v),         hp[2 * k],     sp);
                sp = fmaf(bf2f((u16)(v >> 16)), hp[2 * k + 1], sp);
            }
        }
        part[w][lane] = sp;
    }
    __syncthreads();
    if (t < LL) sc_s[t] = part[(t >> 6) << 1][t & 63] + part[((t >> 6) << 1) + 1][t & 63];
    __syncthreads();

    if (w == 0) {
        float v0 = sc_s[lane];
        float v1 = (lane + 64 < LL) ? sc_s[lane + 64] : -1e30f;
        float m = fmaxf(v0, v1);
#pragma unroll
        for (int s = 1; s < 64; s <<= 1) m = fmaxf(m, __shfl_xor(m, s));
        float e0 = __expf(v0 - m);
        float e1 = (lane + 64 < LL) ? __expf(v1 - m) : 0.f;
        float ssum = e0 + e1;
#pragma unroll
        for (int s = 1; s < 64; s <<= 1) ssum += __shfl_xor(ssum, s);
        float inv = 1.f / ssum;
        al_s[lane] = e0 * inv;
        if (lane + 64 < LL) al_s[lane + 64] = e1 * inv;
    }
    __syncthreads();

    // ctx: wave-split l (25 each), lanes cover 256 cols
    {
        const int l0 = w * 25;
        float c0 = 0.f, c1 = 0.f, c2 = 0.f, c3 = 0.f;
#pragma unroll
        for (int li = 0; li < 25; ++li) {
            int l = l0 + li;
            float a = al_s[l];
            u32 v0 = enc_u[l * ROWU + lane * 2];
            u32 v1 = enc_u[l * ROWU + lane * 2 + 1];
            c0 = fmaf(a, bf2f((u16)v0), c0);
            c1 = fmaf(a, bf2f((u16)(v0 >> 16)), c1);
            c2 = fmaf(a, bf2f((u16)v1), c2);
            c3 = fmaf(a, bf2f((u16)(v1 >> 16)), c3);
        }
        f32x4 p; p[0] = c0; p[1] = c1; p[2] = c2; p[3] = c3;
        *reinterpret_cast<f32x4*>(&part[w][lane * 4]) = p;
    }
    __syncthreads();
    ctx_out[b * DD + t] = (part[0][t] + part[1][t]) + (part[2][t] + part[3][t]);
    __syncthreads();
    }   // rep
}

// ---------------------------------------------------------------------------
// K-att: att = tanh(concat(h, ctx) @ W_att_vec^T)  (unchanged)
// ---------------------------------------------------------------------------
__global__ __launch_bounds__(256) void k_att(
    const float* __restrict__ h, const float* __restrict__ ctx,
    const float* __restrict__ W_att_vec, float* __restrict__ att_out)
{
    __shared__ __align__(16) float As[16][36];
    __shared__ __align__(16) float Bs[16][68];
    const int t = threadIdx.x;
    const int row0 = blockIdx.x * 32;
    const int col0 = blockIdx.y * 64;
    const int tr = t >> 4, tc = t & 15;
    float acc[2][4] = {};
    for (int kt = 0; kt < 32; ++kt) {
        const float* __restrict__ Asrc = (kt < 16) ? h : ctx;
        int kb = (kt < 16) ? kt * 16 : (kt - 16) * 16;
        int kg = kt * 16;
        __syncthreads();
#pragma unroll
        for (int p = 0; p < 2; ++p) {
            int e = t + p * 256;
            int r = e >> 4, kk = e & 15;
            As[kk][r] = Asrc[(row0 + r) * DD + kb + kk];
        }
#pragma unroll
        for (int p = 0; p < 4; ++p) {
            int e = t + p * 256;
            int r = e >> 4, kk = e & 15;
            Bs[kk][r] = W_att_vec[(col0 + r) * KAV + kg + kk];
        }
        __syncthreads();
#pragma unroll
        for (int kk = 0; kk < 16; ++kk) {
            float a0 = As[kk][tr * 2], a1 = As[kk][tr * 2 + 1];
            f32x4 b = *reinterpret_cast<const f32x4*>(&Bs[kk][tc * 4]);
#pragma unroll
            for (int i = 0; i < 4; ++i) {
                acc[0][i] = fmaf(a0, b[i], acc[0][i]);
                acc[1][i] = fmaf(a1, b[i], acc[1][i]);
            }
        }
    }
#pragma unroll
    for (int j = 0; j < 2; ++j)
#pragma unroll
        for (int i = 0; i < 4; ++i)
            att_out[(row0 + tr * 2 + j) * DD + col0 + tc * 4 + i] = tanhf(acc[j][i]);
}

// ---------------------------------------------------------------------------
// K-ptrproj: [atW | att_p | rule_logits]  (unchanged)
// ---------------------------------------------------------------------------
__global__ __launch_bounds__(256) void k_ptrproj(
    const float* __restrict__ att, const float* __restrict__ W_ptr,
    const float* __restrict__ W_prim_proj, const float* __restrict__ rpT,
    float* __restrict__ atw, u16* __restrict__ att_bf, float* __restrict__ rl)
{
    __shared__ __align__(16) float As[16][36];
    __shared__ __align__(16) float Bs[16][68];
    const int t = threadIdx.x;
    const int row0 = blockIdx.x * 32;
    const int col0 = blockIdx.y * 64;
    const int tr = t >> 4, tc = t & 15;
    float acc[2][4] = {};
    for (int kt = 0; kt < 16; ++kt) {
        __syncthreads();
#pragma unroll
        for (int p = 0; p < 2; ++p) {
            int e = t + p * 256;
            int r = e >> 4, kk = e & 15;
            As[kk][r] = att[(row0 + r) * DD + kt * 16 + kk];
        }
#pragma unroll
        for (int p = 0; p < 4; ++p) {
            int e = t + p * 256;
            int kk = e >> 6, c = e & 63;
            float bv;
            if (col0 < 256)      bv = W_ptr[(kt * 16 + kk) * DD + col0 + c];
            else if (col0 < 384) bv = W_prim_proj[(kt * 16 + kk) * 128 + (col0 - 256) + c];
            else {
                int rc = col0 - 384 + c;
                bv = (rc < RR) ? rpT[(kt * 16 + kk) * 192 + rc] : 0.f;
            }
            Bs[kk][c] = bv;
        }
        __syncthreads();
#pragma unroll
        for (int kk = 0; kk < 16; ++kk) {
            float a0 = As[kk][tr * 2], a1 = As[kk][tr * 2 + 1];
            f32x4 b = *reinterpret_cast<const f32x4*>(&Bs[kk][tc * 4]);
#pragma unroll
            for (int i = 0; i < 4; ++i) {
                acc[0][i] = fmaf(a0, b[i], acc[0][i]);
                acc[1][i] = fmaf(a1, b[i], acc[1][i]);
            }
        }
    }
    if (col0 < 256) {
#pragma unroll
        for (int j = 0; j < 2; ++j) {
            f32x4 v;
#pragma unroll
            for (int i = 0; i < 4; ++i) v[i] = acc[j][i];
            *reinterpret_cast<f32x4*>(&atw[(row0 + tr * 2 + j) * DD + col0 + tc * 4]) = v;
        }
    } else if (col0 < 384) {
#pragma unroll
        for (int j = 0; j < 2; ++j)
#pragma unroll
            for (int i = 0; i < 4; ++i)
                att_bf[(row0 + tr * 2 + j) * 128 + (col0 - 256) + tc * 4 + i] = f2bf(acc[j][i]);
    } else {
#pragma unroll
        for (int j = 0; j < 2; ++j)
#pragma unroll
            for (int i = 0; i < 4; ++i) {
                int rc = col0 - 384 + tc * 4 + i;
                if (rc < RR) rl[(row0 + tr * 2 + j) * 132 + rc] = acc[j][i];
            }
    }
}

// ---------------------------------------------------------------------------
// K-fin: rule log-softmax + gate.  (unchanged)
// ---------------------------------------------------------------------------
__global__ __launch_bounds__(256) void k_fin(
    const float* __restrict__ rl, const float* __restrict__ att,
    const float* __restrict__ w_gen, const float* __restrict__ b_gen,
    float* __restrict__ log_p_rule, float* __restrict__ gate0_ws,
    float* __restrict__ gate1_ws)
{
    const int w = threadIdx.x >> 6, lane = threadIdx.x & 63;
    const int b = blockIdx.x * 4 + w;

    float v0 = rl[b * 132 + lane];
    float v1 = rl[b * 132 + 64 + lane];
    float v2 = (lane == 0) ? rl[b * 132 + 128] : -1e30f;
    float m = fmaxf(fmaxf(v0, v1), v2);
#pragma unroll
    for (int s = 1; s < 64; s <<= 1) m = fmaxf(m, __shfl_xor(m, s));
    float ssum = __expf(v0 - m) + __expf(v1 - m) + ((lane == 0) ? __expf(v2 - m) : 0.f);
#pragma unroll
    for (int s = 1; s < 64; s <<= 1) ssum += __shfl_xor(ssum, s);
    float ls = m + logf(ssum);
    log_p_rule[b * RR + lane] = v0 - ls;
    log_p_rule[b * RR + 64 + lane] = v1 - ls;
    if (lane == 0) log_p_rule[b * RR + 128] = v2 - ls;

    f32x4 a4 = *reinterpret_cast<const f32x4*>(&att[b * DD + lane * 4]);
    f32x4 g0 = *reinterpret_cast<const f32x4*>(&w_gen[lane * 4]);
    f32x4 g1 = *reinterpret_cast<const f32x4*>(&w_gen[DD + lane * 4]);
    float p0 = a4[0] * g0[0] + a4[1] * g0[1] + a4[2] * g0[2] + a4[3] * g0[3];
    float p1 = a4[0] * g1[0] + a4[1] * g1[1] + a4[2] * g1[2] + a4[3] * g1[3];
#pragma unroll
    for (int s = 1; s < 64; s <<= 1) { p0 += __shfl_xor(p0, s); p1 += __shfl_xor(p1, s); }
    if (lane == 0) {
        float ga = p0 + b_gen[0], gb = p1 + b_gen[1];
        float gm = fmaxf(ga, gb);
        float ea = __expf(ga - gm), eb = __expf(gb - gm);
        gate0_ws[b] = ea / (ea + eb);
        gate1_ws[b] = eb / (ea + eb);
    }
}

// ---------------------------------------------------------------------------
// K-ptr2 [AMPLIFIED x reps for diagnostics — body idempotent, trailing barrier]
// ---------------------------------------------------------------------------
__global__ __launch_bounds__(256) void k_ptr2(
    const float* __restrict__ src_enc, const float* __restrict__ atw,
    const float* __restrict__ gate1_ws, float* __restrict__ copy_mass, int reps)
{
    __shared__ float sc_s[LL];
    const int b = blockIdx.x, t = threadIdx.x;
    const int lane = t & 63, w = t >> 6;
    const float* __restrict__ enc = src_enc + (size_t)b * LL * DD;

    for (int rep = 0; rep < reps; ++rep) {
    f32x4 aw4 = *reinterpret_cast<const f32x4*>(&atw[b * DD + lane * 4]);

    for (int l = w; l < LL; l += 4) {
        f32x4 ev = *reinterpret_cast<const f32x4*>(&enc[l * DD + lane * 4]);
        float pr = aw4[0] * ev[0] + aw4[1] * ev[1] + aw4[2] * ev[2] + aw4[3] * ev[3];
#pragma unroll
        for (int m = 1; m < 64; m <<= 1) pr += __shfl_xor(pr, m);
        if (lane == 0) sc_s[l] = pr;
    }
    __syncthreads();
    if (w == 0) {
        float gate1 = gate1_ws[b];
        float v0 = sc_s[lane];
        float v1 = (lane + 64 < LL) ? sc_s[lane + 64] : -1e30f;
        float m = fmaxf(v0, v1);
#pragma unroll
        for (int s = 1; s < 64; s <<= 1) m = fmaxf(m, __shfl_xor(m, s));
        float ee0 = __expf(v0 - m);
        float ee1 = (lane + 64 < LL) ? __expf(v1 - m) : 0.f;
        float ssum = ee0 + ee1;
#pragma unroll
        for (int s = 1; s < 64; s <<= 1) ssum += __shfl_xor(ssum, s);
        float inv = 1.f / ssum;
        copy_mass[b * LL + lane] = gate1 * ee0 * inv;
        if (lane + 64 < LL) copy_mass[b * LL + lane + 64] = gate1 * ee1 * inv;
    }
    __syncthreads();
    }   // rep
}

// ---------------------------------------------------------------------------
// K7 [AMPLIFIED x reps for diagnostics — body idempotent, no LDS]
// ---------------------------------------------------------------------------
template <int PASS>
__global__ __launch_bounds__(256) void k_prim(
    const u16* __restrict__ att_bf, const u16* __restrict__ prim_bf,
    const float* __restrict__ coef, float* __restrict__ stats, float* __restrict__ p_prim,
    int reps)
{
    const int t = threadIdx.x;
    const int lane = t & 63, w = t >> 6;
    const int lm = lane & 15, lq = lane >> 4;
    const int colbase = blockIdx.x * 128 + (w & 1) * 64;
    const int chunk = colbase >> 6;
    const int rowblk = blockIdx.y * 256;

    for (int rep = 0; rep < reps; ++rep) {
    s16x8 pfr[4][4];
#pragma unroll
    for (int kg = 0; kg < 4; ++kg)
#pragma unroll
        for (int mg = 0; mg < 4; ++mg)
            pfr[kg][mg] = *reinterpret_cast<const s16x8*>(
                &prim_bf[(size_t)(colbase + mg * 16 + lm) * 128 + kg * 32 + lq * 8]);

    for (int it = 0; it < 2; ++it) {
        const int rowbase = rowblk + it * 128 + (w >> 1) * 64;
        f32x4 acc[4][4] = {};
#pragma unroll
        for (int kg = 0; kg < 4; ++kg) {
            s16x8 afr[4];
#pragma unroll
            for (int ng = 0; ng < 4; ++ng)
                afr[ng] = *reinterpret_cast<const s16x8*>(
                    &att_bf[(rowbase + ng * 16 + lm) * 128 + kg * 32 + lq * 8]);
#pragma unroll
            for (int mg = 0; mg < 4; ++mg)
#pragma unroll
                for (int ng = 0; ng < 4; ++ng)
                    acc[mg][ng] = __builtin_amdgcn_mfma_f32_16x16x32_bf16(
                        pfr[kg][mg], afr[ng], acc[mg][ng], 0, 0, 0);
        }
        if (PASS == 0) {
#pragma unroll
            for (int ng = 0; ng < 4; ++ng) {
                float se = 0.f;
#pragma unroll
                for (int mg = 0; mg < 4; ++mg)
                    se += __expf(acc[mg][ng][0]) + __expf(acc[mg][ng][1])
                        + __expf(acc[mg][ng][2]) + __expf(acc[mg][ng][3]);
                se += __shfl_xor(se, 16);
                se += __shfl_xor(se, 32);
                if (lq == 0)
                    stats[chunk * NB + rowbase + ng * 16 + lm] = se;
            }
        } else {
#pragma unroll
            for (int ng = 0; ng < 4; ++ng) {
                const int arow = rowbase + ng * 16 + lm;
                const float cf = coef[arow];
                float* __restrict__ dst = &p_prim[(size_t)arow * VV + colbase + lq * 4];
#pragma unroll
                for (int mg = 0; mg < 4; ++mg) {
                    f32x4 v;
                    v[0] = cf * __expf(acc[mg][ng][0]);
                    v[1] = cf * __expf(acc[mg][ng][1]);
                    v[2] = cf * __expf(acc[mg][ng][2]);
                    v[3] = cf * __expf(acc[mg][ng][3]);
                    *reinterpret_cast<f32x4*>(&dst[mg * 16]) = v;
                }
            }
        }
    }
    }   // rep
}

// ---------------------------------------------------------------------------
// K8: combine chunk-major sumexp -> coef = gate0/total (unchanged)
// ---------------------------------------------------------------------------
__global__ __launch_bounds__(256) void k_combine(
    const float* __restrict__ stats, const float* __restrict__ gate0_ws,
    float* __restrict__ coef)
{
    const int row = blockIdx.x * 256 + threadIdx.x;
    float s0 = 0.f, s1 = 0.f, s2 = 0.f, s3 = 0.f;
    for (int c = 0; c < 500; c += 4) {
        s0 += stats[(c)     * NB + row];
        s1 += stats[(c + 1) * NB + row];
        s2 += stats[(c + 2) * NB + row];
        s3 += stats[(c + 3) * NB + row];
    }
    coef[row] = gate0_ws[row] / ((s0 + s1) + (s2 + s3));
}

// ---------------------------------------------------------------------------
// K9: scatter copy mass into p_prim rows (unchanged)
// ---------------------------------------------------------------------------
__global__ __launch_bounds__(256) void k_scatter(
    const int* __restrict__ tok, const float* __restrict__ copy_mass, float* __restrict__ p_prim)
{
    int i = blockIdx.x * 256 + threadIdx.x;
    if (i >= NB * LL) return;
    int b = i / LL;
    atomicAdd(&p_prim[(size_t)b * VV + tok[i]], copy_mass[i]);
}

// ---------------------------------------------------------------------------
extern "C" void kernel_launch(void* const* d_in, const int* in_sizes, int n_in,
                              void* d_out, int out_size, void* d_ws, size_t ws_size,
                              hipStream_t stream)
{
    const float* x         = (const float*)d_in[0];
    const float* h0        = (const float*)d_in[1];
    const float* c0        = (const float*)d_in[2];
    const float* src_enc   = (const float*)d_in[3];
    const int*   tok       = (const int*)  d_in[4];
    const float* W_ih      = (const float*)d_in[5];
    const float* b_ih      = (const float*)d_in[6];
    const float* W_hh      = (const float*)d_in[7];
    const float* b_hh      = (const float*)d_in[8];
    const float* W_attn    = (const float*)d_in[9];
    const float* W_att_vec = (const float*)d_in[10];
    const float* W_ptr     = (const float*)d_in[11];
    const float* rule_emb  = (const float*)d_in[12];
    const float* W_rule_pr = (const float*)d_in[13];
    const float* prim_emb  = (const float*)d_in[14];
    const float* W_prim_pr = (const float*)d_in[15];
    const float* w_gen     = (const float*)d_in[16];
    const float* b_gen     = (const float*)d_in[17];

    float* out    = (float*)d_out;
    float* o_logp = out;                               // [1024,129]
    float* o_pp   = out + 1024 * 129;                  // [1024,32000]
    float* o_h    = o_pp + (size_t)1024 * 32000;       // [1024,256]
    float* o_c    = o_h + 1024 * 256;                  // [1024,256]
    float* o_att  = o_c + 1024 * 256;                  // [1024,256]

    float* wsf      = (float*)d_ws;
    float* ws_rpT   = wsf;                     // 49152
    float* ws_rl    = ws_rpT   + 49152;        // 135168
    float* ws_gate0 = ws_rl    + 135168;       // 1024
    float* ws_gate1 = ws_gate0 + 1024;         // 1024
    float* ws_cm    = ws_gate1 + 1024;         // 102400
    float* ws_coef  = ws_cm    + 102400;       // 1024
    float* ws_hw    = ws_coef  + 1024;         // 262144
    float* ws_ctx   = ws_hw    + 262144;       // 262144
    float* ws_atw   = ws_ctx   + 262144;       // 262144
    float* ws_stats = ws_atw   + 262144;       // 512000
    u16*   ub       = (u16*)(ws_stats + 512000);
    u16*   ws_attbf = ub;                      // 131,072
    u16*   ws_primbf= ws_attbf + 131072;       // 4,096,000
    u16*   ws_xb    = ws_primbf + 4096000;     // 720,896
    u16*   ws_h0b   = ws_xb    + 720896;       // 262,144
    u16*   ws_wihb  = ws_h0b   + 262144;       // 720,896
    u16*   ws_whhb  = ws_wihb  + 720896;       // 262,144

    k_conv<<<dim3(2960), 256, 0, stream>>>(prim_emb, ws_primbf, W_ih, ws_wihb,
                                           W_hh, ws_whhb, x, ws_xb, h0, ws_h0b,
                                           rule_emb, W_rule_pr, ws_rpT);
    k_lstm<<<dim3(16, 8), 256, 0, stream>>>(ws_xb, ws_h0b, c0, ws_wihb, ws_whhb,
                                            b_ih, b_hh, o_h, o_c);
    k_hw<<<dim3(32, 4), 256, 0, stream>>>(o_h, W_attn, ws_hw);
    k_attn2<<<dim3(1024), 256, 0, stream>>>(src_enc, ws_hw, ws_ctx, 8);
    k_att<<<dim3(32, 4), 256, 0, stream>>>(o_h, ws_ctx, W_att_vec, o_att);
    k_ptrproj<<<dim3(32, 9), 256, 0, stream>>>(o_att, W_ptr, W_prim_pr, ws_rpT,
                                               ws_atw, ws_attbf, ws_rl);
    k_fin<<<dim3(256), 256, 0, stream>>>(ws_rl, o_att, w_gen, b_gen,
                                         o_logp, ws_gate0, ws_gate1);
    k_ptr2<<<dim3(1024), 256, 0, stream>>>(src_enc, ws_atw, ws_gate1, ws_cm, 8);
    k_prim<0><<<dim3(250, 4), 256, 0, stream>>>(ws_attbf, ws_primbf, nullptr, ws_stats, nullptr, 3);
    k_combine<<<dim3(4), 256, 0, stream>>>(ws_stats, ws_gate0, ws_coef);
    k_prim<1><<<dim3(250, 4), 256, 0, stream>>>(ws_attbf, ws_primbf, ws_coef, nullptr, o_pp, 3);
    k_scatter<<<dim3(400), 256, 0, stream>>>(tok, ws_cm, o_pp);
}

// Round 13
// 246.843 us; speedup vs baseline: 1.9198x; 1.9198x over previous
//
#include <hip/hip_runtime.h>
#include <hip/hip_bf16.h>
#include <math.h>

#define NB   1024
#define LL   100
#define DD   256
#define DINN 704
#define VV   32000
#define RR   129
#define KAV  512
#define ROWU 129   // enc LDS row stride in dwords (odd => conflict-free)

typedef float f32x4 __attribute__((ext_vector_type(4)));
typedef short s16x8 __attribute__((ext_vector_type(8)));
typedef unsigned short u16;
typedef unsigned int u32;

__device__ __forceinline__ float sigf(float x) { return 1.0f / (1.0f + __expf(-x)); }

__device__ __forceinline__ u16 f2bf(float f) {
    u32 u = __float_as_uint(f);
    u += 0x7fffu + ((u >> 16) & 1u);
    return (u16)(u >> 16);
}
__device__ __forceinline__ float bf2f(u16 s) {
    return __uint_as_float(((u32)s) << 16);
}
__device__ __forceinline__ s16x8 pack8(const float* __restrict__ p) {
    f32x4 a = *reinterpret_cast<const f32x4*>(p);
    f32x4 b = *reinterpret_cast<const f32x4*>(p + 4);
    s16x8 r;
    r[0] = (short)f2bf(a[0]); r[1] = (short)f2bf(a[1]);
    r[2] = (short)f2bf(a[2]); r[3] = (short)f2bf(a[3]);
    r[4] = (short)f2bf(b[0]); r[5] = (short)f2bf(b[1]);
    r[6] = (short)f2bf(b[2]); r[7] = (short)f2bf(b[3]);
    return r;
}

// ---------------------------------------------------------------------------
// K-head: blocks [0,128): LSTM via bf16 MFMA with INLINE fp32->bf16 packing
//         (identical f2bf rounding as the old pre-conversion path).
//         blocks [128,2128): prim_emb fp32->bf16.
//         blocks [2128,2257): rule_proj^T.
// ---------------------------------------------------------------------------
__global__ __launch_bounds__(256) void k_head(
    const float* __restrict__ x, const float* __restrict__ h0,
    const float* __restrict__ c0,
    const float* __restrict__ W_ih, const float* __restrict__ W_hh,
    const float* __restrict__ b_ih, const float* __restrict__ b_hh,
    float* __restrict__ out_h, float* __restrict__ out_c,
    const float* __restrict__ prim_emb, u16* __restrict__ prim_bf,
    const float* __restrict__ rule_emb, const float* __restrict__ W_rule_proj,
    float* __restrict__ rpT)
{
    __shared__ float re_s[128];
    const int bx = blockIdx.x, t = threadIdx.x;

    if (bx >= 2128) {                       // rule_proj^T
        const int r = bx - 2128;
        if (t < 128) re_s[t] = rule_emb[r * 128 + t];
        __syncthreads();
        float acc = 0.f;
        const float* __restrict__ wr = &W_rule_proj[t * 128];
#pragma unroll 8
        for (int k = 0; k < 128; k += 4) {
            f32x4 w4 = *reinterpret_cast<const f32x4*>(&wr[k]);
            acc += w4[0] * re_s[k] + w4[1] * re_s[k + 1]
                 + w4[2] * re_s[k + 2] + w4[3] * re_s[k + 3];
        }
        rpT[t * 192 + r] = acc;
        return;
    }
    if (bx >= 128) {                        // prim_emb conversion
        int i = (bx - 128) * 2048 + t * 8;
        *reinterpret_cast<s16x8*>(&prim_bf[i]) = pack8(&prim_emb[i]);
        return;
    }

    // ---- LSTM, inline-packed MFMA ----
    const int lane = t & 63, w = t >> 6;
    const int lm = lane & 15, lq = lane >> 4;
    const int dg = bx & 15;
    const int row0 = (bx >> 4) * 128 + w * 32;
    f32x4 acc[4][2] = {};

    for (int kt = 0; kt < 22; ++kt) {
        const int ko = kt * 32 + lq * 8;
        s16x8 bfr[4], afr[2];
#pragma unroll
        for (int mg = 0; mg < 4; ++mg)
            bfr[mg] = pack8(&W_ih[(mg * 256 + dg * 16 + lm) * DINN + ko]);
#pragma unroll
        for (int ng = 0; ng < 2; ++ng)
            afr[ng] = pack8(&x[(row0 + ng * 16 + lm) * DINN + ko]);
#pragma unroll
        for (int mg = 0; mg < 4; ++mg)
#pragma unroll
            for (int ng = 0; ng < 2; ++ng)
                acc[mg][ng] = __builtin_amdgcn_mfma_f32_16x16x32_bf16(
                    bfr[mg], afr[ng], acc[mg][ng], 0, 0, 0);
    }
    for (int kt = 0; kt < 8; ++kt) {
        const int ko = kt * 32 + lq * 8;
        s16x8 bfr[4], afr[2];
#pragma unroll
        for (int mg = 0; mg < 4; ++mg)
            bfr[mg] = pack8(&W_hh[(mg * 256 + dg * 16 + lm) * DD + ko]);
#pragma unroll
        for (int ng = 0; ng < 2; ++ng)
            afr[ng] = pack8(&h0[(row0 + ng * 16 + lm) * DD + ko]);
#pragma unroll
        for (int mg = 0; mg < 4; ++mg)
#pragma unroll
            for (int ng = 0; ng < 2; ++ng)
                acc[mg][ng] = __builtin_amdgcn_mfma_f32_16x16x32_bf16(
                    bfr[mg], afr[ng], acc[mg][ng], 0, 0, 0);
    }

    const int dc = dg * 16 + lq * 4;
    f32x4 bi[4];
#pragma unroll
    for (int mg = 0; mg < 4; ++mg) {
        f32x4 a4 = *reinterpret_cast<const f32x4*>(&b_ih[mg * 256 + dc]);
        f32x4 b4 = *reinterpret_cast<const f32x4*>(&b_hh[mg * 256 + dc]);
        bi[mg][0] = a4[0] + b4[0]; bi[mg][1] = a4[1] + b4[1];
        bi[mg][2] = a4[2] + b4[2]; bi[mg][3] = a4[3] + b4[3];
    }
#pragma unroll
    for (int ng = 0; ng < 2; ++ng) {
        const int row = row0 + ng * 16 + lm;
        f32x4 c4 = *reinterpret_cast<const f32x4*>(&c0[row * DD + dc]);
        f32x4 h4, cc4;
#pragma unroll
        for (int r = 0; r < 4; ++r) {
            float iv = acc[0][ng][r] + bi[0][r];
            float fv = acc[1][ng][r] + bi[1][r];
            float gv = acc[2][ng][r] + bi[2][r];
            float ov = acc[3][ng][r] + bi[3][r];
            float cc = sigf(fv) * c4[r] + sigf(iv) * tanhf(gv);
            cc4[r] = cc;
            h4[r] = sigf(ov) * tanhf(cc);
        }
        *reinterpret_cast<f32x4*>(&out_c[row * DD + dc]) = cc4;
        *reinterpret_cast<f32x4*>(&out_h[row * DD + dc]) = h4;
    }
}

// ---------------------------------------------------------------------------
// K-attn2b: hW inline (wave-split matvec, W_attn L2-resident) + scores +
// softmax + ctx. enc staged once (bf16, odd-stride LDS).
// ---------------------------------------------------------------------------
__global__ __launch_bounds__(256, 2) void k_attn2b(
    const float* __restrict__ src_enc, const float* __restrict__ h,
    const float* __restrict__ W_attn, float* __restrict__ ctx_out)
{
    __shared__ u32 enc_u[LL * ROWU];
    __shared__ __align__(16) float part[4][DD];
    __shared__ __align__(16) float h_s[DD];
    __shared__ __align__(16) float hw_s[DD];
    __shared__ float sc_s[LL];
    __shared__ float al_s[LL];

    const int b = blockIdx.x, t = threadIdx.x;
    const int lane = t & 63, w = t >> 6;
    const float* __restrict__ enc = src_enc + (size_t)b * LL * DD;

    h_s[t] = h[b * DD + t];

#pragma unroll
    for (int p = 0; p < 25; ++p) {
        int q = p * 256 + t;
        int l = q >> 6, dq = q & 63;
        f32x4 ev = *reinterpret_cast<const f32x4*>(&enc[l * DD + dq * 4]);
        u32 w0 = (u32)f2bf(ev[0]) | ((u32)f2bf(ev[1]) << 16);
        u32 w1 = (u32)f2bf(ev[2]) | ((u32)f2bf(ev[3]) << 16);
        enc_u[l * ROWU + dq * 2]     = w0;
        enc_u[l * ROWU + dq * 2 + 1] = w1;
    }
    __syncthreads();

    // hW = h @ W_attn : wave w owns k-slice, lanes cover all 256 cols
    {
        f32x4 p = {0.f, 0.f, 0.f, 0.f};
        const int e0 = w * 64;
#pragma unroll 4
        for (int e = e0; e < e0 + 64; ++e) {
            float hv = h_s[e];
            f32x4 wv = *reinterpret_cast<const f32x4*>(&W_attn[e * DD + lane * 4]);
            p[0] = fmaf(hv, wv[0], p[0]); p[1] = fmaf(hv, wv[1], p[1]);
            p[2] = fmaf(hv, wv[2], p[2]); p[3] = fmaf(hv, wv[3], p[3]);
        }
        *reinterpret_cast<f32x4*>(&part[w][lane * 4]) = p;
    }
    __syncthreads();
    hw_s[t] = (part[0][t] + part[1][t]) + (part[2][t] + part[3][t]);
    __syncthreads();

    // scores: lane-per-l, wave pair splits d
    {
        const int sl = ((w >> 1) << 6) + lane;
        float sp = 0.f;
        if (sl < LL) {
            const u32* __restrict__ rp = enc_u + sl * ROWU + ((w & 1) << 6);
            const float* __restrict__ hp = hw_s + ((w & 1) << 7);
#pragma unroll 32
            for (int k = 0; k < 64; ++k) {
                u32 v = rp[k];
                sp = fmaf(bf2f((u16)v),         hp[2 * k],     sp);
                sp = fmaf(bf2f((u16)(v >> 16)), hp[2 * k + 1], sp);
            }
        }
        part[w][lane] = sp;
    }
    __syncthreads();
    if (t < LL) sc_s[t] = part[(t >> 6) << 1][t & 63] + part[((t >> 6) << 1) + 1][t & 63];
    __syncthreads();

    if (w == 0) {
        float v0 = sc_s[lane];
        float v1 = (lane + 64 < LL) ? sc_s[lane + 64] : -1e30f;
        float m = fmaxf(v0, v1);
#pragma unroll
        for (int s = 1; s < 64; s <<= 1) m = fmaxf(m, __shfl_xor(m, s));
        float e0 = __expf(v0 - m);
        float e1 = (lane + 64 < LL) ? __expf(v1 - m) : 0.f;
        float ssum = e0 + e1;
#pragma unroll
        for (int s = 1; s < 64; s <<= 1) ssum += __shfl_xor(ssum, s);
        float inv = 1.f / ssum;
        al_s[lane] = e0 * inv;
        if (lane + 64 < LL) al_s[lane + 64] = e1 * inv;
    }
    __syncthreads();

    // ctx: wave-split l (25 each), lanes cover 256 cols
    {
        const int l0 = w * 25;
        float c0 = 0.f, c1 = 0.f, c2 = 0.f, c3 = 0.f;
#pragma unroll
        for (int li = 0; li < 25; ++li) {
            int l = l0 + li;
            float a = al_s[l];
            u32 v0 = enc_u[l * ROWU + lane * 2];
            u32 v1 = enc_u[l * ROWU + lane * 2 + 1];
            c0 = fmaf(a, bf2f((u16)v0), c0);
            c1 = fmaf(a, bf2f((u16)(v0 >> 16)), c1);
            c2 = fmaf(a, bf2f((u16)v1), c2);
            c3 = fmaf(a, bf2f((u16)(v1 >> 16)), c3);
        }
        f32x4 p; p[0] = c0; p[1] = c1; p[2] = c2; p[3] = c3;
        *reinterpret_cast<f32x4*>(&part[w][lane * 4]) = p;
    }
    __syncthreads();
    ctx_out[b * DD + t] = (part[0][t] + part[1][t]) + (part[2][t] + part[3][t]);
}

// ---------------------------------------------------------------------------
// K-att: att = tanh(concat(h, ctx) @ W_att_vec^T), 32-row tiles, grid (32,4)
// ---------------------------------------------------------------------------
__global__ __launch_bounds__(256) void k_att(
    const float* __restrict__ h, const float* __restrict__ ctx,
    const float* __restrict__ W_att_vec, float* __restrict__ att_out)
{
    __shared__ __align__(16) float As[16][36];
    __shared__ __align__(16) float Bs[16][68];
    const int t = threadIdx.x;
    const int row0 = blockIdx.x * 32;
    const int col0 = blockIdx.y * 64;
    const int tr = t >> 4, tc = t & 15;
    float acc[2][4] = {};
    for (int kt = 0; kt < 32; ++kt) {
        const float* __restrict__ Asrc = (kt < 16) ? h : ctx;
        int kb = (kt < 16) ? kt * 16 : (kt - 16) * 16;
        int kg = kt * 16;
        __syncthreads();
#pragma unroll
        for (int p = 0; p < 2; ++p) {
            int e = t + p * 256;
            int r = e >> 4, kk = e & 15;
            As[kk][r] = Asrc[(row0 + r) * DD + kb + kk];
        }
#pragma unroll
        for (int p = 0; p < 4; ++p) {
            int e = t + p * 256;
            int r = e >> 4, kk = e & 15;
            Bs[kk][r] = W_att_vec[(col0 + r) * KAV + kg + kk];
        }
        __syncthreads();
#pragma unroll
        for (int kk = 0; kk < 16; ++kk) {
            float a0 = As[kk][tr * 2], a1 = As[kk][tr * 2 + 1];
            f32x4 b = *reinterpret_cast<const f32x4*>(&Bs[kk][tc * 4]);
#pragma unroll
            for (int i = 0; i < 4; ++i) {
                acc[0][i] = fmaf(a0, b[i], acc[0][i]);
                acc[1][i] = fmaf(a1, b[i], acc[1][i]);
            }
        }
    }
#pragma unroll
    for (int j = 0; j < 2; ++j)
#pragma unroll
        for (int i = 0; i < 4; ++i)
            att_out[(row0 + tr * 2 + j) * DD + col0 + tc * 4 + i] = tanhf(acc[j][i]);
}

// ---------------------------------------------------------------------------
// K-ptrproj: [atW | att_p | rule_logits] = att @ [W_ptr | W_prim_proj | rpT]
// grid (32, 9).
// ---------------------------------------------------------------------------
__global__ __launch_bounds__(256) void k_ptrproj(
    const float* __restrict__ att, const float* __restrict__ W_ptr,
    const float* __restrict__ W_prim_proj, const float* __restrict__ rpT,
    float* __restrict__ atw, u16* __restrict__ att_bf, float* __restrict__ rl)
{
    __shared__ __align__(16) float As[16][36];
    __shared__ __align__(16) float Bs[16][68];
    const int t = threadIdx.x;
    const int row0 = blockIdx.x * 32;
    const int col0 = blockIdx.y * 64;
    const int tr = t >> 4, tc = t & 15;
    float acc[2][4] = {};
    for (int kt = 0; kt < 16; ++kt) {
        __syncthreads();
#pragma unroll
        for (int p = 0; p < 2; ++p) {
            int e = t + p * 256;
            int r = e >> 4, kk = e & 15;
            As[kk][r] = att[(row0 + r) * DD + kt * 16 + kk];
        }
#pragma unroll
        for (int p = 0; p < 4; ++p) {
            int e = t + p * 256;
            int kk = e >> 6, c = e & 63;
            float bv;
            if (col0 < 256)      bv = W_ptr[(kt * 16 + kk) * DD + col0 + c];
            else if (col0 < 384) bv = W_prim_proj[(kt * 16 + kk) * 128 + (col0 - 256) + c];
            else {
                int rc = col0 - 384 + c;
                bv = (rc < RR) ? rpT[(kt * 16 + kk) * 192 + rc] : 0.f;
            }
            Bs[kk][c] = bv;
        }
        __syncthreads();
#pragma unroll
        for (int kk = 0; kk < 16; ++kk) {
            float a0 = As[kk][tr * 2], a1 = As[kk][tr * 2 + 1];
            f32x4 b = *reinterpret_cast<const f32x4*>(&Bs[kk][tc * 4]);
#pragma unroll
            for (int i = 0; i < 4; ++i) {
                acc[0][i] = fmaf(a0, b[i], acc[0][i]);
                acc[1][i] = fmaf(a1, b[i], acc[1][i]);
            }
        }
    }
    if (col0 < 256) {
#pragma unroll
        for (int j = 0; j < 2; ++j) {
            f32x4 v;
#pragma unroll
            for (int i = 0; i < 4; ++i) v[i] = acc[j][i];
            *reinterpret_cast<f32x4*>(&atw[(row0 + tr * 2 + j) * DD + col0 + tc * 4]) = v;
        }
    } else if (col0 < 384) {
#pragma unroll
        for (int j = 0; j < 2; ++j)
#pragma unroll
            for (int i = 0; i < 4; ++i)
                att_bf[(row0 + tr * 2 + j) * 128 + (col0 - 256) + tc * 4 + i] = f2bf(acc[j][i]);
    } else {
#pragma unroll
        for (int j = 0; j < 2; ++j)
#pragma unroll
            for (int i = 0; i < 4; ++i) {
                int rc = col0 - 384 + tc * 4 + i;
                if (rc < RR) rl[(row0 + tr * 2 + j) * 132 + rc] = acc[j][i];
            }
    }
}

// ---------------------------------------------------------------------------
// K-back: 3 independent consumers of ptrproj, fused by block range.
//   [0,256):      fin (rule log-softmax + gate)
//   [256,1280):   ptr2 (scores + softmax, UNGATED copy probs)
//   [1280,2280):  prim0 (sumexp stats)
// ---------------------------------------------------------------------------
__global__ __launch_bounds__(256) void k_back(
    const float* __restrict__ rl, const float* __restrict__ att,
    const float* __restrict__ w_gen, const float* __restrict__ b_gen,
    float* __restrict__ log_p_rule, float* __restrict__ gate0_ws,
    float* __restrict__ gate1_ws,
    const float* __restrict__ src_enc, const float* __restrict__ atw,
    float* __restrict__ copy_mass,
    const u16* __restrict__ att_bf, const u16* __restrict__ prim_bf,
    float* __restrict__ stats)
{
    __shared__ float sc_s[LL];
    const int bx = blockIdx.x, t = threadIdx.x;
    const int lane = t & 63, w = t >> 6;

    if (bx < 256) {     // ---- fin ----
        const int b = bx * 4 + w;
        float v0 = rl[b * 132 + lane];
        float v1 = rl[b * 132 + 64 + lane];
        float v2 = (lane == 0) ? rl[b * 132 + 128] : -1e30f;
        float m = fmaxf(fmaxf(v0, v1), v2);
#pragma unroll
        for (int s = 1; s < 64; s <<= 1) m = fmaxf(m, __shfl_xor(m, s));
        float ssum = __expf(v0 - m) + __expf(v1 - m) + ((lane == 0) ? __expf(v2 - m) : 0.f);
#pragma unroll
        for (int s = 1; s < 64; s <<= 1) ssum += __shfl_xor(ssum, s);
        float ls = m + logf(ssum);
        log_p_rule[b * RR + lane] = v0 - ls;
        log_p_rule[b * RR + 64 + lane] = v1 - ls;
        if (lane == 0) log_p_rule[b * RR + 128] = v2 - ls;

        f32x4 a4 = *reinterpret_cast<const f32x4*>(&att[b * DD + lane * 4]);
        f32x4 g0 = *reinterpret_cast<const f32x4*>(&w_gen[lane * 4]);
        f32x4 g1 = *reinterpret_cast<const f32x4*>(&w_gen[DD + lane * 4]);
        float p0 = a4[0] * g0[0] + a4[1] * g0[1] + a4[2] * g0[2] + a4[3] * g0[3];
        float p1 = a4[0] * g1[0] + a4[1] * g1[1] + a4[2] * g1[2] + a4[3] * g1[3];
#pragma unroll
        for (int s = 1; s < 64; s <<= 1) { p0 += __shfl_xor(p0, s); p1 += __shfl_xor(p1, s); }
        if (lane == 0) {
            float ga = p0 + b_gen[0], gb = p1 + b_gen[1];
            float gm = fmaxf(ga, gb);
            float ea = __expf(ga - gm), eb = __expf(gb - gm);
            gate0_ws[b] = ea / (ea + eb);
            gate1_ws[b] = eb / (ea + eb);
        }
        return;
    }

    if (bx < 1280) {    // ---- ptr2 (ungated) ----
        const int b = bx - 256;
        const float* __restrict__ enc = src_enc + (size_t)b * LL * DD;
        f32x4 aw4 = *reinterpret_cast<const f32x4*>(&atw[b * DD + lane * 4]);

        for (int l = w; l < LL; l += 4) {
            f32x4 ev = *reinterpret_cast<const f32x4*>(&enc[l * DD + lane * 4]);
            float pr = aw4[0] * ev[0] + aw4[1] * ev[1] + aw4[2] * ev[2] + aw4[3] * ev[3];
#pragma unroll
            for (int m = 1; m < 64; m <<= 1) pr += __shfl_xor(pr, m);
            if (lane == 0) sc_s[l] = pr;
        }
        __syncthreads();
        if (w == 0) {
            float v0 = sc_s[lane];
            float v1 = (lane + 64 < LL) ? sc_s[lane + 64] : -1e30f;
            float m = fmaxf(v0, v1);
#pragma unroll
            for (int s = 1; s < 64; s <<= 1) m = fmaxf(m, __shfl_xor(m, s));
            float ee0 = __expf(v0 - m);
            float ee1 = (lane + 64 < LL) ? __expf(v1 - m) : 0.f;
            float ssum = ee0 + ee1;
#pragma unroll
            for (int s = 1; s < 64; s <<= 1) ssum += __shfl_xor(ssum, s);
            float inv = 1.f / ssum;
            copy_mass[b * LL + lane] = ee0 * inv;
            if (lane + 64 < LL) copy_mass[b * LL + lane + 64] = ee1 * inv;
        }
        return;
    }

    // ---- prim0 ----
    {
        const int cb = bx - 1280;           // 0..999
        const int colb = cb % 250, rowblk = cb / 250;
        const int lm = lane & 15, lq = lane >> 4;
        const int colbase = colb * 128 + (w & 1) * 64;
        const int chunk = colbase >> 6;
        const int rowblk_g = rowblk * 256;

        s16x8 pfr[4][4];
#pragma unroll
        for (int kg = 0; kg < 4; ++kg)
#pragma unroll
            for (int mg = 0; mg < 4; ++mg)
                pfr[kg][mg] = *reinterpret_cast<const s16x8*>(
                    &prim_bf[(size_t)(colbase + mg * 16 + lm) * 128 + kg * 32 + lq * 8]);

        for (int it = 0; it < 2; ++it) {
            const int rowbase = rowblk_g + it * 128 + (w >> 1) * 64;
            f32x4 acc[4][4] = {};
#pragma unroll
            for (int kg = 0; kg < 4; ++kg) {
                s16x8 afr[4];
#pragma unroll
                for (int ng = 0; ng < 4; ++ng)
                    afr[ng] = *reinterpret_cast<const s16x8*>(
                        &att_bf[(rowbase + ng * 16 + lm) * 128 + kg * 32 + lq * 8]);
#pragma unroll
                for (int mg = 0; mg < 4; ++mg)
#pragma unroll
                    for (int ng = 0; ng < 4; ++ng)
                        acc[mg][ng] = __builtin_amdgcn_mfma_f32_16x16x32_bf16(
                            pfr[kg][mg], afr[ng], acc[mg][ng], 0, 0, 0);
            }
#pragma unroll
            for (int ng = 0; ng < 4; ++ng) {
                float se = 0.f;
#pragma unroll
                for (int mg = 0; mg < 4; ++mg)
                    se += __expf(acc[mg][ng][0]) + __expf(acc[mg][ng][1])
                        + __expf(acc[mg][ng][2]) + __expf(acc[mg][ng][3]);
                se += __shfl_xor(se, 16);
                se += __shfl_xor(se, 32);
                if (lq == 0)
                    stats[chunk * NB + rowbase + ng * 16 + lm] = se;
            }
        }
    }
}

// ---------------------------------------------------------------------------
// K-prim1: p_prim write pass (bf16 MFMA, f32x4 stores).
// ---------------------------------------------------------------------------
__global__ __launch_bounds__(256) void k_prim1(
    const u16* __restrict__ att_bf, const u16* __restrict__ prim_bf,
    const float* __restrict__ coef, float* __restrict__ p_prim)
{
    const int t = threadIdx.x;
    const int lane = t & 63, w = t >> 6;
    const int lm = lane & 15, lq = lane >> 4;
    const int colbase = blockIdx.x * 128 + (w & 1) * 64;
    const int rowblk = blockIdx.y * 256;

    s16x8 pfr[4][4];
#pragma unroll
    for (int kg = 0; kg < 4; ++kg)
#pragma unroll
        for (int mg = 0; mg < 4; ++mg)
            pfr[kg][mg] = *reinterpret_cast<const s16x8*>(
                &prim_bf[(size_t)(colbase + mg * 16 + lm) * 128 + kg * 32 + lq * 8]);

    for (int it = 0; it < 2; ++it) {
        const int rowbase = rowblk + it * 128 + (w >> 1) * 64;
        f32x4 acc[4][4] = {};
#pragma unroll
        for (int kg = 0; kg < 4; ++kg) {
            s16x8 afr[4];
#pragma unroll
            for (int ng = 0; ng < 4; ++ng)
                afr[ng] = *reinterpret_cast<const s16x8*>(
                    &att_bf[(rowbase + ng * 16 + lm) * 128 + kg * 32 + lq * 8]);
#pragma unroll
            for (int mg = 0; mg < 4; ++mg)
#pragma unroll
                for (int ng = 0; ng < 4; ++ng)
                    acc[mg][ng] = __builtin_amdgcn_mfma_f32_16x16x32_bf16(
                        pfr[kg][mg], afr[ng], acc[mg][ng], 0, 0, 0);
        }
#pragma unroll
        for (int ng = 0; ng < 4; ++ng) {
            const int arow = rowbase + ng * 16 + lm;
            const float cf = coef[arow];
            float* __restrict__ dst = &p_prim[(size_t)arow * VV + colbase + lq * 4];
#pragma unroll
            for (int mg = 0; mg < 4; ++mg) {
                f32x4 v;
                v[0] = cf * __expf(acc[mg][ng][0]);
                v[1] = cf * __expf(acc[mg][ng][1]);
                v[2] = cf * __expf(acc[mg][ng][2]);
                v[3] = cf * __expf(acc[mg][ng][3]);
                *reinterpret_cast<f32x4*>(&dst[mg * 16]) = v;
            }
        }
    }
}

// ---------------------------------------------------------------------------
// K8: combine chunk-major sumexp -> coef = gate0/total (coalesced).
// ---------------------------------------------------------------------------
__global__ __launch_bounds__(256) void k_combine(
    const float* __restrict__ stats, const float* __restrict__ gate0_ws,
    float* __restrict__ coef)
{
    const int row = blockIdx.x * 256 + threadIdx.x;
    float s0 = 0.f, s1 = 0.f, s2 = 0.f, s3 = 0.f;
    for (int c = 0; c < 500; c += 4) {
        s0 += stats[(c)     * NB + row];
        s1 += stats[(c + 1) * NB + row];
        s2 += stats[(c + 2) * NB + row];
        s3 += stats[(c + 3) * NB + row];
    }
    coef[row] = gate0_ws[row] / ((s0 + s1) + (s2 + s3));
}

// ---------------------------------------------------------------------------
// K9: scatter (applies gate1 here; copy_mass is ungated)
// ---------------------------------------------------------------------------
__global__ __launch_bounds__(256) void k_scatter(
    const int* __restrict__ tok, const float* __restrict__ copy_mass,
    const float* __restrict__ gate1_ws, float* __restrict__ p_prim)
{
    int i = blockIdx.x * 256 + threadIdx.x;
    if (i >= NB * LL) return;
    int b = i / LL;
    atomicAdd(&p_prim[(size_t)b * VV + tok[i]], gate1_ws[b] * copy_mass[i]);
}

// ---------------------------------------------------------------------------
extern "C" void kernel_launch(void* const* d_in, const int* in_sizes, int n_in,
                              void* d_out, int out_size, void* d_ws, size_t ws_size,
                              hipStream_t stream)
{
    const float* x         = (const float*)d_in[0];
    const float* h0        = (const float*)d_in[1];
    const float* c0        = (const float*)d_in[2];
    const float* src_enc   = (const float*)d_in[3];
    const int*   tok       = (const int*)  d_in[4];
    const float* W_ih      = (const float*)d_in[5];
    const float* b_ih      = (const float*)d_in[6];
    const float* W_hh      = (const float*)d_in[7];
    const float* b_hh      = (const float*)d_in[8];
    const float* W_attn    = (const float*)d_in[9];
    const float* W_att_vec = (const float*)d_in[10];
    const float* W_ptr     = (const float*)d_in[11];
    const float* rule_emb  = (const float*)d_in[12];
    const float* W_rule_pr = (const float*)d_in[13];
    const float* prim_emb  = (const float*)d_in[14];
    const float* W_prim_pr = (const float*)d_in[15];
    const float* w_gen     = (const float*)d_in[16];
    const float* b_gen     = (const float*)d_in[17];

    float* out    = (float*)d_out;
    float* o_logp = out;                               // [1024,129]
    float* o_pp   = out + 1024 * 129;                  // [1024,32000]
    float* o_h    = o_pp + (size_t)1024 * 32000;       // [1024,256]
    float* o_c    = o_h + 1024 * 256;                  // [1024,256]
    float* o_att  = o_c + 1024 * 256;                  // [1024,256]

    float* wsf      = (float*)d_ws;
    float* ws_rpT   = wsf;                     // 49152
    float* ws_rl    = ws_rpT   + 49152;        // 135168
    float* ws_gate0 = ws_rl    + 135168;       // 1024
    float* ws_gate1 = ws_gate0 + 1024;         // 1024
    float* ws_cm    = ws_gate1 + 1024;         // 102400
    float* ws_coef  = ws_cm    + 102400;       // 1024
    float* ws_ctx   = ws_coef  + 1024;         // 262144
    float* ws_atw   = ws_ctx   + 262144;       // 262144
    float* ws_stats = ws_atw   + 262144;       // 512000
    u16*   ws_attbf = (u16*)(ws_stats + 512000);       // 131,072
    u16*   ws_primbf= ws_attbf + 131072;               // 4,096,000
    // total ~ 14 MB

    k_head<<<dim3(2257), 256, 0, stream>>>(x, h0, c0, W_ih, W_hh, b_ih, b_hh,
                                           o_h, o_c, prim_emb, ws_primbf,
                                           rule_emb, W_rule_pr, ws_rpT);
    k_attn2b<<<dim3(1024), 256, 0, stream>>>(src_enc, o_h, W_attn, ws_ctx);
    k_att<<<dim3(32, 4), 256, 0, stream>>>(o_h, ws_ctx, W_att_vec, o_att);
    k_ptrproj<<<dim3(32, 9), 256, 0, stream>>>(o_att, W_ptr, W_prim_pr, ws_rpT,
                                               ws_atw, ws_attbf, ws_rl);
    k_back<<<dim3(2280), 256, 0, stream>>>(ws_rl, o_att, w_gen, b_gen,
                                           o_logp, ws_gate0, ws_gate1,
                                           src_enc, ws_atw, ws_cm,
                                           ws_attbf, ws_primbf, ws_stats);
    k_combine<<<dim3(4), 256, 0, stream>>>(ws_stats, ws_gate0, ws_coef);
    k_prim1<<<dim3(250, 4), 256, 0, stream>>>(ws_attbf, ws_primbf, ws_coef, o_pp);
    k_scatter<<<dim3(400), 256, 0, stream>>>(tok, ws_cm, ws_gate1, o_pp);
}

// Round 14
// 240.747 us; speedup vs baseline: 1.9684x; 1.0253x over previous
//
#include <hip/hip_runtime.h>
#include <hip/hip_bf16.h>
#include <math.h>

#define NB   1024
#define LL   100
#define DD   256
#define DINN 704
#define VV   32000
#define RR   129
#define KAV  512
#define ROWU 129   // enc LDS row stride in dwords (odd => conflict-free)

typedef float f32x4 __attribute__((ext_vector_type(4)));
typedef short s16x8 __attribute__((ext_vector_type(8)));
typedef unsigned short u16;
typedef unsigned int u32;

__device__ __forceinline__ float sigf(float x) { return 1.0f / (1.0f + __expf(-x)); }

__device__ __forceinline__ u16 f2bf(float f) {
    u32 u = __float_as_uint(f);
    u += 0x7fffu + ((u >> 16) & 1u);
    return (u16)(u >> 16);
}
__device__ __forceinline__ float bf2f(u16 s) {
    return __uint_as_float(((u32)s) << 16);
}

// ---------------------------------------------------------------------------
// K-conv: fp32->bf16 conversions (prim_emb, W_ih, W_hh, x, h0) + rule_proj^T.
// (R11-proven)
// ---------------------------------------------------------------------------
__global__ __launch_bounds__(256) void k_conv(
    const float* __restrict__ prim_emb, u16* __restrict__ prim_bf,
    const float* __restrict__ W_ih, u16* __restrict__ wih_bf,
    const float* __restrict__ W_hh, u16* __restrict__ whh_bf,
    const float* __restrict__ x, u16* __restrict__ x_bf,
    const float* __restrict__ h0, u16* __restrict__ h0_bf,
    const float* __restrict__ rule_emb, const float* __restrict__ W_rule_proj,
    float* __restrict__ rpT)
{
    __shared__ float re_s[128];
    const int bx = blockIdx.x, t = threadIdx.x;

    const float* src; u16* dst; int off;
    if (bx < 2000)      { src = prim_emb; dst = prim_bf; off = bx * 2048; }
    else if (bx < 2352) { src = W_ih;  dst = wih_bf; off = (bx - 2000) * 2048; }
    else if (bx < 2480) { src = W_hh;  dst = whh_bf; off = (bx - 2352) * 2048; }
    else if (bx < 2832) { src = x;     dst = x_bf;   off = (bx - 2480) * 2048; }
    else                { src = h0;    dst = h0_bf;  off = (bx - 2832) * 2048; }

    if (bx < RR && t < 128) re_s[t] = rule_emb[bx * 128 + t];

    int i = off + t * 8;
    f32x4 a = *reinterpret_cast<const f32x4*>(&src[i]);
    f32x4 b = *reinterpret_cast<const f32x4*>(&src[i + 4]);
    s16x8 r;
    r[0] = (short)f2bf(a[0]); r[1] = (short)f2bf(a[1]);
    r[2] = (short)f2bf(a[2]); r[3] = (short)f2bf(a[3]);
    r[4] = (short)f2bf(b[0]); r[5] = (short)f2bf(b[1]);
    r[6] = (short)f2bf(b[2]); r[7] = (short)f2bf(b[3]);
    *reinterpret_cast<s16x8*>(&dst[i]) = r;

    if (bx < RR) {
        __syncthreads();
        float acc = 0.f;
        const float* __restrict__ wr = &W_rule_proj[t * 128];
#pragma unroll 8
        for (int k = 0; k < 128; k += 4) {
            f32x4 w4 = *reinterpret_cast<const f32x4*>(&wr[k]);
            acc += w4[0] * re_s[k] + w4[1] * re_s[k + 1]
                 + w4[2] * re_s[k + 2] + w4[3] * re_s[k + 3];
        }
        rpT[t * 192 + bx] = acc;     // transposed [256][192-padded]
    }
}

// ---------------------------------------------------------------------------
// K1: LSTM via bf16 MFMA (R11-proven).
// ---------------------------------------------------------------------------
__global__ __launch_bounds__(256) void k_lstm(
    const u16* __restrict__ x_bf, const u16* __restrict__ h0_bf,
    const float* __restrict__ c0,
    const u16* __restrict__ wih_bf, const u16* __restrict__ whh_bf,
    const float* __restrict__ b_ih, const float* __restrict__ b_hh,
    float* __restrict__ out_h, float* __restrict__ out_c)
{
    const int t = threadIdx.x;
    const int lane = t & 63, w = t >> 6;
    const int lm = lane & 15, lq = lane >> 4;
    const int dg = blockIdx.x;
    const int row0 = blockIdx.y * 128 + w * 32;
    f32x4 acc[4][2] = {};

    for (int kt = 0; kt < 22; ++kt) {
        const int ko = kt * 32 + lq * 8;
        s16x8 bfr[4], afr[2];
#pragma unroll
        for (int mg = 0; mg < 4; ++mg)
            bfr[mg] = *reinterpret_cast<const s16x8*>(
                &wih_bf[(mg * 256 + dg * 16 + lm) * DINN + ko]);
#pragma unroll
        for (int ng = 0; ng < 2; ++ng)
            afr[ng] = *reinterpret_cast<const s16x8*>(
                &x_bf[(row0 + ng * 16 + lm) * DINN + ko]);
#pragma unroll
        for (int mg = 0; mg < 4; ++mg)
#pragma unroll
            for (int ng = 0; ng < 2; ++ng)
                acc[mg][ng] = __builtin_amdgcn_mfma_f32_16x16x32_bf16(
                    bfr[mg], afr[ng], acc[mg][ng], 0, 0, 0);
    }
    for (int kt = 0; kt < 8; ++kt) {
        const int ko = kt * 32 + lq * 8;
        s16x8 bfr[4], afr[2];
#pragma unroll
        for (int mg = 0; mg < 4; ++mg)
            bfr[mg] = *reinterpret_cast<const s16x8*>(
                &whh_bf[(mg * 256 + dg * 16 + lm) * DD + ko]);
#pragma unroll
        for (int ng = 0; ng < 2; ++ng)
            afr[ng] = *reinterpret_cast<const s16x8*>(
                &h0_bf[(row0 + ng * 16 + lm) * DD + ko]);
#pragma unroll
        for (int mg = 0; mg < 4; ++mg)
#pragma unroll
            for (int ng = 0; ng < 2; ++ng)
                acc[mg][ng] = __builtin_amdgcn_mfma_f32_16x16x32_bf16(
                    bfr[mg], afr[ng], acc[mg][ng], 0, 0, 0);
    }

    const int dc = dg * 16 + lq * 4;
    f32x4 bi[4];
#pragma unroll
    for (int mg = 0; mg < 4; ++mg) {
        f32x4 a4 = *reinterpret_cast<const f32x4*>(&b_ih[mg * 256 + dc]);
        f32x4 b4 = *reinterpret_cast<const f32x4*>(&b_hh[mg * 256 + dc]);
        bi[mg][0] = a4[0] + b4[0]; bi[mg][1] = a4[1] + b4[1];
        bi[mg][2] = a4[2] + b4[2]; bi[mg][3] = a4[3] + b4[3];
    }
#pragma unroll
    for (int ng = 0; ng < 2; ++ng) {
        const int row = row0 + ng * 16 + lm;
        f32x4 c4 = *reinterpret_cast<const f32x4*>(&c0[row * DD + dc]);
        f32x4 h4, cc4;
#pragma unroll
        for (int r = 0; r < 4; ++r) {
            float iv = acc[0][ng][r] + bi[0][r];
            float fv = acc[1][ng][r] + bi[1][r];
            float gv = acc[2][ng][r] + bi[2][r];
            float ov = acc[3][ng][r] + bi[3][r];
            float cc = sigf(fv) * c4[r] + sigf(iv) * tanhf(gv);
            cc4[r] = cc;
            h4[r] = sigf(ov) * tanhf(cc);
        }
        *reinterpret_cast<f32x4*>(&out_c[row * DD + dc]) = cc4;
        *reinterpret_cast<f32x4*>(&out_h[row * DD + dc]) = h4;
    }
}

// ---------------------------------------------------------------------------
// K-hw: hW = h @ W_attn  (GEMM, R8-proven)
// ---------------------------------------------------------------------------
__global__ __launch_bounds__(256) void k_hw(
    const float* __restrict__ h, const float* __restrict__ W_attn, float* __restrict__ hW)
{
    __shared__ __align__(16) float As[16][36];
    __shared__ __align__(16) float Bs[16][68];
    const int t = threadIdx.x;
    const int row0 = blockIdx.x * 32;
    const int col0 = blockIdx.y * 64;
    const int tr = t >> 4, tc = t & 15;
    float acc[2][4] = {};
    for (int kt = 0; kt < 16; ++kt) {
        __syncthreads();
#pragma unroll
        for (int p = 0; p < 2; ++p) {
            int e = t + p * 256;
            int r = e >> 4, kk = e & 15;
            As[kk][r] = h[(row0 + r) * DD + kt * 16 + kk];
        }
#pragma unroll
        for (int p = 0; p < 4; ++p) {
            int e = t + p * 256;
            int kk = e >> 6, c = e & 63;
            Bs[kk][c] = W_attn[(kt * 16 + kk) * DD + col0 + c];
        }
        __syncthreads();
#pragma unroll
        for (int kk = 0; kk < 16; ++kk) {
            float a0 = As[kk][tr * 2], a1 = As[kk][tr * 2 + 1];
            f32x4 b = *reinterpret_cast<const f32x4*>(&Bs[kk][tc * 4]);
#pragma unroll
            for (int i = 0; i < 4; ++i) {
                acc[0][i] = fmaf(a0, b[i], acc[0][i]);
                acc[1][i] = fmaf(a1, b[i], acc[1][i]);
            }
        }
    }
#pragma unroll
    for (int j = 0; j < 2; ++j) {
        f32x4 v;
#pragma unroll
        for (int i = 0; i < 4; ++i) v[i] = acc[j][i];
        *reinterpret_cast<f32x4*>(&hW[(row0 + tr * 2 + j) * DD + col0 + tc * 4]) = v;
    }
}

// ---------------------------------------------------------------------------
// K-attn2: per-b scores + softmax + ctx. enc staged once (bf16). (R11-proven)
// ---------------------------------------------------------------------------
__global__ __launch_bounds__(256, 2) void k_attn2(
    const float* __restrict__ src_enc, const float* __restrict__ hW,
    float* __restrict__ ctx_out)
{
    __shared__ u32 enc_u[LL * ROWU];
    __shared__ __align__(16) float part[4][DD];
    __shared__ __align__(16) float hw_s[DD];
    __shared__ float sc_s[LL];
    __shared__ float al_s[LL];

    const int b = blockIdx.x, t = threadIdx.x;
    const int lane = t & 63, w = t >> 6;
    const float* __restrict__ enc = src_enc + (size_t)b * LL * DD;

    hw_s[t] = hW[b * DD + t];

#pragma unroll
    for (int p = 0; p < 25; ++p) {
        int q = p * 256 + t;
        int l = q >> 6, dq = q & 63;
        f32x4 ev = *reinterpret_cast<const f32x4*>(&enc[l * DD + dq * 4]);
        u32 w0 = (u32)f2bf(ev[0]) | ((u32)f2bf(ev[1]) << 16);
        u32 w1 = (u32)f2bf(ev[2]) | ((u32)f2bf(ev[3]) << 16);
        enc_u[l * ROWU + dq * 2]     = w0;
        enc_u[l * ROWU + dq * 2 + 1] = w1;
    }
    __syncthreads();

    {
        const int sl = ((w >> 1) << 6) + lane;
        float sp = 0.f;
        if (sl < LL) {
            const u32* __restrict__ rp = enc_u + sl * ROWU + ((w & 1) << 6);
            const float* __restrict__ hp = hw_s + ((w & 1) << 7);
#pragma unroll 32
            for (int k = 0; k < 64; ++k) {
                u32 v = rp[k];
                sp = fmaf(bf2f((u16)v),         hp[2 * k],     sp);
                sp = fmaf(bf2f((u16)(v >> 16)), hp[2 * k + 1], sp);
            }
        }
        part[w][lane] = sp;
    }
    __syncthreads();
    if (t < LL) sc_s[t] = part[(t >> 6) << 1][t & 63] + part[((t >> 6) << 1) + 1][t & 63];
    __syncthreads();

    if (w == 0) {
        float v0 = sc_s[lane];
        float v1 = (lane + 64 < LL) ? sc_s[lane + 64] : -1e30f;
        float m = fmaxf(v0, v1);
#pragma unroll
        for (int s = 1; s < 64; s <<= 1) m = fmaxf(m, __shfl_xor(m, s));
        float e0 = __expf(v0 - m);
        float e1 = (lane + 64 < LL) ? __expf(v1 - m) : 0.f;
        float ssum = e0 + e1;
#pragma unroll
        for (int s = 1; s < 64; s <<= 1) ssum += __shfl_xor(ssum, s);
        float inv = 1.f / ssum;
        al_s[lane] = e0 * inv;
        if (lane + 64 < LL) al_s[lane + 64] = e1 * inv;
    }
    __syncthreads();

    {
        const int l0 = w * 25;
        float c0 = 0.f, c1 = 0.f, c2 = 0.f, c3 = 0.f;
#pragma unroll
        for (int li = 0; li < 25; ++li) {
            int l = l0 + li;
            float a = al_s[l];
            u32 v0 = enc_u[l * ROWU + lane * 2];
            u32 v1 = enc_u[l * ROWU + lane * 2 + 1];
            c0 = fmaf(a, bf2f((u16)v0), c0);
            c1 = fmaf(a, bf2f((u16)(v0 >> 16)), c1);
            c2 = fmaf(a, bf2f((u16)v1), c2);
            c3 = fmaf(a, bf2f((u16)(v1 >> 16)), c3);
        }
        f32x4 p; p[0] = c0; p[1] = c1; p[2] = c2; p[3] = c3;
        *reinterpret_cast<f32x4*>(&part[w][lane * 4]) = p;
    }
    __syncthreads();
    ctx_out[b * DD + t] = (part[0][t] + part[1][t]) + (part[2][t] + part[3][t]);
}

// ---------------------------------------------------------------------------
// K-att: att = tanh(concat(h, ctx) @ W_att_vec^T), 32-row tiles, grid (32,4)
// ---------------------------------------------------------------------------
__global__ __launch_bounds__(256) void k_att(
    const float* __restrict__ h, const float* __restrict__ ctx,
    const float* __restrict__ W_att_vec, float* __restrict__ att_out)
{
    __shared__ __align__(16) float As[16][36];
    __shared__ __align__(16) float Bs[16][68];
    const int t = threadIdx.x;
    const int row0 = blockIdx.x * 32;
    const int col0 = blockIdx.y * 64;
    const int tr = t >> 4, tc = t & 15;
    float acc[2][4] = {};
    for (int kt = 0; kt < 32; ++kt) {
        const float* __restrict__ Asrc = (kt < 16) ? h : ctx;
        int kb = (kt < 16) ? kt * 16 : (kt - 16) * 16;
        int kg = kt * 16;
        __syncthreads();
#pragma unroll
        for (int p = 0; p < 2; ++p) {
            int e = t + p * 256;
            int r = e >> 4, kk = e & 15;
            As[kk][r] = Asrc[(row0 + r) * DD + kb + kk];
        }
#pragma unroll
        for (int p = 0; p < 4; ++p) {
            int e = t + p * 256;
            int r = e >> 4, kk = e & 15;
            Bs[kk][r] = W_att_vec[(col0 + r) * KAV + kg + kk];
        }
        __syncthreads();
#pragma unroll
        for (int kk = 0; kk < 16; ++kk) {
            float a0 = As[kk][tr * 2], a1 = As[kk][tr * 2 + 1];
            f32x4 b = *reinterpret_cast<const f32x4*>(&Bs[kk][tc * 4]);
#pragma unroll
            for (int i = 0; i < 4; ++i) {
                acc[0][i] = fmaf(a0, b[i], acc[0][i]);
                acc[1][i] = fmaf(a1, b[i], acc[1][i]);
            }
        }
    }
#pragma unroll
    for (int j = 0; j < 2; ++j)
#pragma unroll
        for (int i = 0; i < 4; ++i)
            att_out[(row0 + tr * 2 + j) * DD + col0 + tc * 4 + i] = tanhf(acc[j][i]);
}

// ---------------------------------------------------------------------------
// K-ptrproj: [atW | att_p | rule_logits] = att @ [W_ptr | W_prim_proj | rpT]
// grid (32, 9).
// ---------------------------------------------------------------------------
__global__ __launch_bounds__(256) void k_ptrproj(
    const float* __restrict__ att, const float* __restrict__ W_ptr,
    const float* __restrict__ W_prim_proj, const float* __restrict__ rpT,
    float* __restrict__ atw, u16* __restrict__ att_bf, float* __restrict__ rl)
{
    __shared__ __align__(16) float As[16][36];
    __shared__ __align__(16) float Bs[16][68];
    const int t = threadIdx.x;
    const int row0 = blockIdx.x * 32;
    const int col0 = blockIdx.y * 64;
    const int tr = t >> 4, tc = t & 15;
    float acc[2][4] = {};
    for (int kt = 0; kt < 16; ++kt) {
        __syncthreads();
#pragma unroll
        for (int p = 0; p < 2; ++p) {
            int e = t + p * 256;
            int r = e >> 4, kk = e & 15;
            As[kk][r] = att[(row0 + r) * DD + kt * 16 + kk];
        }
#pragma unroll
        for (int p = 0; p < 4; ++p) {
            int e = t + p * 256;
            int kk = e >> 6, c = e & 63;
            float bv;
            if (col0 < 256)      bv = W_ptr[(kt * 16 + kk) * DD + col0 + c];
            else if (col0 < 384) bv = W_prim_proj[(kt * 16 + kk) * 128 + (col0 - 256) + c];
            else {
                int rc = col0 - 384 + c;
                bv = (rc < RR) ? rpT[(kt * 16 + kk) * 192 + rc] : 0.f;
            }
            Bs[kk][c] = bv;
        }
        __syncthreads();
#pragma unroll
        for (int kk = 0; kk < 16; ++kk) {
            float a0 = As[kk][tr * 2], a1 = As[kk][tr * 2 + 1];
            f32x4 b = *reinterpret_cast<const f32x4*>(&Bs[kk][tc * 4]);
#pragma unroll
            for (int i = 0; i < 4; ++i) {
                acc[0][i] = fmaf(a0, b[i], acc[0][i]);
                acc[1][i] = fmaf(a1, b[i], acc[1][i]);
            }
        }
    }
    if (col0 < 256) {
#pragma unroll
        for (int j = 0; j < 2; ++j) {
            f32x4 v;
#pragma unroll
            for (int i = 0; i < 4; ++i) v[i] = acc[j][i];
            *reinterpret_cast<f32x4*>(&atw[(row0 + tr * 2 + j) * DD + col0 + tc * 4]) = v;
        }
    } else if (col0 < 384) {
#pragma unroll
        for (int j = 0; j < 2; ++j)
#pragma unroll
            for (int i = 0; i < 4; ++i)
                att_bf[(row0 + tr * 2 + j) * 128 + (col0 - 256) + tc * 4 + i] = f2bf(acc[j][i]);
    } else {
#pragma unroll
        for (int j = 0; j < 2; ++j)
#pragma unroll
            for (int i = 0; i < 4; ++i) {
                int rc = col0 - 384 + tc * 4 + i;
                if (rc < RR) rl[(row0 + tr * 2 + j) * 132 + rc] = acc[j][i];
            }
    }
}

// ---------------------------------------------------------------------------
// K-back: 3 independent consumers of ptrproj, fused by block range.
//   [0,256):      fin (rule log-softmax + gate)
//   [256,1280):   ptr2 (scores + softmax, UNGATED copy probs)
//   [1280,2280):  prim0 (sumexp stats)
// ---------------------------------------------------------------------------
__global__ __launch_bounds__(256) void k_back(
    const float* __restrict__ rl, const float* __restrict__ att,
    const float* __restrict__ w_gen, const float* __restrict__ b_gen,
    float* __restrict__ log_p_rule, float* __restrict__ gate0_ws,
    float* __restrict__ gate1_ws,
    const float* __restrict__ src_enc, const float* __restrict__ atw,
    float* __restrict__ copy_mass,
    const u16* __restrict__ att_bf, const u16* __restrict__ prim_bf,
    float* __restrict__ stats)
{
    __shared__ float sc_s[LL];
    const int bx = blockIdx.x, t = threadIdx.x;
    const int lane = t & 63, w = t >> 6;

    if (bx < 256) {     // ---- fin ----
        const int b = bx * 4 + w;
        float v0 = rl[b * 132 + lane];
        float v1 = rl[b * 132 + 64 + lane];
        float v2 = (lane == 0) ? rl[b * 132 + 128] : -1e30f;
        float m = fmaxf(fmaxf(v0, v1), v2);
#pragma unroll
        for (int s = 1; s < 64; s <<= 1) m = fmaxf(m, __shfl_xor(m, s));
        float ssum = __expf(v0 - m) + __expf(v1 - m) + ((lane == 0) ? __expf(v2 - m) : 0.f);
#pragma unroll
        for (int s = 1; s < 64; s <<= 1) ssum += __shfl_xor(ssum, s);
        float ls = m + logf(ssum);
        log_p_rule[b * RR + lane] = v0 - ls;
        log_p_rule[b * RR + 64 + lane] = v1 - ls;
        if (lane == 0) log_p_rule[b * RR + 128] = v2 - ls;

        f32x4 a4 = *reinterpret_cast<const f32x4*>(&att[b * DD + lane * 4]);
        f32x4 g0 = *reinterpret_cast<const f32x4*>(&w_gen[lane * 4]);
        f32x4 g1 = *reinterpret_cast<const f32x4*>(&w_gen[DD + lane * 4]);
        float p0 = a4[0] * g0[0] + a4[1] * g0[1] + a4[2] * g0[2] + a4[3] * g0[3];
        float p1 = a4[0] * g1[0] + a4[1] * g1[1] + a4[2] * g1[2] + a4[3] * g1[3];
#pragma unroll
        for (int s = 1; s < 64; s <<= 1) { p0 += __shfl_xor(p0, s); p1 += __shfl_xor(p1, s); }
        if (lane == 0) {
            float ga = p0 + b_gen[0], gb = p1 + b_gen[1];
            float gm = fmaxf(ga, gb);
            float ea = __expf(ga - gm), eb = __expf(gb - gm);
            gate0_ws[b] = ea / (ea + eb);
            gate1_ws[b] = eb / (ea + eb);
        }
        return;
    }

    if (bx < 1280) {    // ---- ptr2 (ungated) ----
        const int b = bx - 256;
        const float* __restrict__ enc = src_enc + (size_t)b * LL * DD;
        f32x4 aw4 = *reinterpret_cast<const f32x4*>(&atw[b * DD + lane * 4]);

        for (int l = w; l < LL; l += 4) {
            f32x4 ev = *reinterpret_cast<const f32x4*>(&enc[l * DD + lane * 4]);
            float pr = aw4[0] * ev[0] + aw4[1] * ev[1] + aw4[2] * ev[2] + aw4[3] * ev[3];
#pragma unroll
            for (int m = 1; m < 64; m <<= 1) pr += __shfl_xor(pr, m);
            if (lane == 0) sc_s[l] = pr;
        }
        __syncthreads();
        if (w == 0) {
            float v0 = sc_s[lane];
            float v1 = (lane + 64 < LL) ? sc_s[lane + 64] : -1e30f;
            float m = fmaxf(v0, v1);
#pragma unroll
            for (int s = 1; s < 64; s <<= 1) m = fmaxf(m, __shfl_xor(m, s));
            float ee0 = __expf(v0 - m);
            float ee1 = (lane + 64 < LL) ? __expf(v1 - m) : 0.f;
            float ssum = ee0 + ee1;
#pragma unroll
            for (int s = 1; s < 64; s <<= 1) ssum += __shfl_xor(ssum, s);
            float inv = 1.f / ssum;
            copy_mass[b * LL + lane] = ee0 * inv;
            if (lane + 64 < LL) copy_mass[b * LL + lane + 64] = ee1 * inv;
        }
        return;
    }

    // ---- prim0 ----
    {
        const int cb = bx - 1280;           // 0..999
        const int colb = cb % 250, rowblk = cb / 250;
        const int lm = lane & 15, lq = lane >> 4;
        const int colbase = colb * 128 + (w & 1) * 64;
        const int chunk = colbase >> 6;
        const int rowblk_g = rowblk * 256;

        s16x8 pfr[4][4];
#pragma unroll
        for (int kg = 0; kg < 4; ++kg)
#pragma unroll
            for (int mg = 0; mg < 4; ++mg)
                pfr[kg][mg] = *reinterpret_cast<const s16x8*>(
                    &prim_bf[(size_t)(colbase + mg * 16 + lm) * 128 + kg * 32 + lq * 8]);

        for (int it = 0; it < 2; ++it) {
            const int rowbase = rowblk_g + it * 128 + (w >> 1) * 64;
            f32x4 acc[4][4] = {};
#pragma unroll
            for (int kg = 0; kg < 4; ++kg) {
                s16x8 afr[4];
#pragma unroll
                for (int ng = 0; ng < 4; ++ng)
                    afr[ng] = *reinterpret_cast<const s16x8*>(
                        &att_bf[(rowbase + ng * 16 + lm) * 128 + kg * 32 + lq * 8]);
#pragma unroll
                for (int mg = 0; mg < 4; ++mg)
#pragma unroll
                    for (int ng = 0; ng < 4; ++ng)
                        acc[mg][ng] = __builtin_amdgcn_mfma_f32_16x16x32_bf16(
                            pfr[kg][mg], afr[ng], acc[mg][ng], 0, 0, 0);
            }
#pragma unroll
            for (int ng = 0; ng < 4; ++ng) {
                float se = 0.f;
#pragma unroll
                for (int mg = 0; mg < 4; ++mg)
                    se += __expf(acc[mg][ng][0]) + __expf(acc[mg][ng][1])
                        + __expf(acc[mg][ng][2]) + __expf(acc[mg][ng][3]);
                se += __shfl_xor(se, 16);
                se += __shfl_xor(se, 32);
                if (lq == 0)
                    stats[chunk * NB + rowbase + ng * 16 + lm] = se;
            }
        }
    }
}

// ---------------------------------------------------------------------------
// K-prim1: p_prim write pass (bf16 MFMA, f32x4 stores).
// ---------------------------------------------------------------------------
__global__ __launch_bounds__(256) void k_prim1(
    const u16* __restrict__ att_bf, const u16* __restrict__ prim_bf,
    const float* __restrict__ coef, float* __restrict__ p_prim)
{
    const int t = threadIdx.x;
    const int lane = t & 63, w = t >> 6;
    const int lm = lane & 15, lq = lane >> 4;
    const int colbase = blockIdx.x * 128 + (w & 1) * 64;
    const int rowblk = blockIdx.y * 256;

    s16x8 pfr[4][4];
#pragma unroll
    for (int kg = 0; kg < 4; ++kg)
#pragma unroll
        for (int mg = 0; mg < 4; ++mg)
            pfr[kg][mg] = *reinterpret_cast<const s16x8*>(
                &prim_bf[(size_t)(colbase + mg * 16 + lm) * 128 + kg * 32 + lq * 8]);

    for (int it = 0; it < 2; ++it) {
        const int rowbase = rowblk + it * 128 + (w >> 1) * 64;
        f32x4 acc[4][4] = {};
#pragma unroll
        for (int kg = 0; kg < 4; ++kg) {
            s16x8 afr[4];
#pragma unroll
            for (int ng = 0; ng < 4; ++ng)
                afr[ng] = *reinterpret_cast<const s16x8*>(
                    &att_bf[(rowbase + ng * 16 + lm) * 128 + kg * 32 + lq * 8]);
#pragma unroll
            for (int mg = 0; mg < 4; ++mg)
#pragma unroll
                for (int ng = 0; ng < 4; ++ng)
                    acc[mg][ng] = __builtin_amdgcn_mfma_f32_16x16x32_bf16(
                        pfr[kg][mg], afr[ng], acc[mg][ng], 0, 0, 0);
        }
#pragma unroll
        for (int ng = 0; ng < 4; ++ng) {
            const int arow = rowbase + ng * 16 + lm;
            const float cf = coef[arow];
            float* __restrict__ dst = &p_prim[(size_t)arow * VV + colbase + lq * 4];
#pragma unroll
            for (int mg = 0; mg < 4; ++mg) {
                f32x4 v;
                v[0] = cf * __expf(acc[mg][ng][0]);
                v[1] = cf * __expf(acc[mg][ng][1]);
                v[2] = cf * __expf(acc[mg][ng][2]);
                v[3] = cf * __expf(acc[mg][ng][3]);
                *reinterpret_cast<f32x4*>(&dst[mg * 16]) = v;
            }
        }
    }
}

// ---------------------------------------------------------------------------
// K8: combine chunk-major sumexp -> coef = gate0/total (coalesced).
// ---------------------------------------------------------------------------
__global__ __launch_bounds__(256) void k_combine(
    const float* __restrict__ stats, const float* __restrict__ gate0_ws,
    float* __restrict__ coef)
{
    const int row = blockIdx.x * 256 + threadIdx.x;
    float s0 = 0.f, s1 = 0.f, s2 = 0.f, s3 = 0.f;
    for (int c = 0; c < 500; c += 4) {
        s0 += stats[(c)     * NB + row];
        s1 += stats[(c + 1) * NB + row];
        s2 += stats[(c + 2) * NB + row];
        s3 += stats[(c + 3) * NB + row];
    }
    coef[row] = gate0_ws[row] / ((s0 + s1) + (s2 + s3));
}

// ---------------------------------------------------------------------------
// K9: scatter (applies gate1 here; copy_mass is ungated)
// ---------------------------------------------------------------------------
__global__ __launch_bounds__(256) void k_scatter(
    const int* __restrict__ tok, const float* __restrict__ copy_mass,
    const float* __restrict__ gate1_ws, float* __restrict__ p_prim)
{
    int i = blockIdx.x * 256 + threadIdx.x;
    if (i >= NB * LL) return;
    int b = i / LL;
    atomicAdd(&p_prim[(size_t)b * VV + tok[i]], gate1_ws[b] * copy_mass[i]);
}

// ---------------------------------------------------------------------------
extern "C" void kernel_launch(void* const* d_in, const int* in_sizes, int n_in,
                              void* d_out, int out_size, void* d_ws, size_t ws_size,
                              hipStream_t stream)
{
    const float* x         = (const float*)d_in[0];
    const float* h0        = (const float*)d_in[1];
    const float* c0        = (const float*)d_in[2];
    const float* src_enc   = (const float*)d_in[3];
    const int*   tok       = (const int*)  d_in[4];
    const float* W_ih      = (const float*)d_in[5];
    const float* b_ih      = (const float*)d_in[6];
    const float* W_hh      = (const float*)d_in[7];
    const float* b_hh      = (const float*)d_in[8];
    const float* W_attn    = (const float*)d_in[9];
    const float* W_att_vec = (const float*)d_in[10];
    const float* W_ptr     = (const float*)d_in[11];
    const float* rule_emb  = (const float*)d_in[12];
    const float* W_rule_pr = (const float*)d_in[13];
    const float* prim_emb  = (const float*)d_in[14];
    const float* W_prim_pr = (const float*)d_in[15];
    const float* w_gen     = (const float*)d_in[16];
    const float* b_gen     = (const float*)d_in[17];

    float* out    = (float*)d_out;
    float* o_logp = out;                               // [1024,129]
    float* o_pp   = out + 1024 * 129;                  // [1024,32000]
    float* o_h    = o_pp + (size_t)1024 * 32000;       // [1024,256]
    float* o_c    = o_h + 1024 * 256;                  // [1024,256]
    float* o_att  = o_c + 1024 * 256;                  // [1024,256]

    float* wsf      = (float*)d_ws;
    float* ws_rpT   = wsf;                     // 49152
    float* ws_rl    = ws_rpT   + 49152;        // 135168
    float* ws_gate0 = ws_rl    + 135168;       // 1024
    float* ws_gate1 = ws_gate0 + 1024;         // 1024
    float* ws_cm    = ws_gate1 + 1024;         // 102400
    float* ws_coef  = ws_cm    + 102400;       // 1024
    float* ws_hw    = ws_coef  + 1024;         // 262144
    float* ws_ctx   = ws_hw    + 262144;       // 262144
    float* ws_atw   = ws_ctx   + 262144;       // 262144
    float* ws_stats = ws_atw   + 262144;       // 512000
    u16*   ub       = (u16*)(ws_stats + 512000);
    u16*   ws_attbf = ub;                      // 131,072
    u16*   ws_primbf= ws_attbf + 131072;       // 4,096,000
    u16*   ws_xb    = ws_primbf + 4096000;     // 720,896
    u16*   ws_h0b   = ws_xb    + 720896;       // 262,144
    u16*   ws_wihb  = ws_h0b   + 262144;       // 720,896
    u16*   ws_whhb  = ws_wihb  + 720896;       // 262,144
    // total ~ 18.7 MB

    k_conv<<<dim3(2960), 256, 0, stream>>>(prim_emb, ws_primbf, W_ih, ws_wihb,
                                           W_hh, ws_whhb, x, ws_xb, h0, ws_h0b,
                                           rule_emb, W_rule_pr, ws_rpT);
    k_lstm<<<dim3(16, 8), 256, 0, stream>>>(ws_xb, ws_h0b, c0, ws_wihb, ws_whhb,
                                            b_ih, b_hh, o_h, o_c);
    k_hw<<<dim3(32, 4), 256, 0, stream>>>(o_h, W_attn, ws_hw);
    k_attn2<<<dim3(1024), 256, 0, stream>>>(src_enc, ws_hw, ws_ctx);
    k_att<<<dim3(32, 4), 256, 0, stream>>>(o_h, ws_ctx, W_att_vec, o_att);
    k_ptrproj<<<dim3(32, 9), 256, 0, stream>>>(o_att, W_ptr, W_prim_pr, ws_rpT,
                                               ws_atw, ws_attbf, ws_rl);
    k_back<<<dim3(2280), 256, 0, stream>>>(ws_rl, o_att, w_gen, b_gen,
                                           o_logp, ws_gate0, ws_gate1,
                                           src_enc, ws_atw, ws_cm,
                                           ws_attbf, ws_primbf, ws_stats);
    k_combine<<<dim3(4), 256, 0, stream>>>(ws_stats, ws_gate0, ws_coef);
    k_prim1<<<dim3(250, 4), 256, 0, stream>>>(ws_attbf, ws_primbf, ws_coef, o_pp);
    k_scatter<<<dim3(400), 256, 0, stream>>>(tok, ws_cm, ws_gate1, o_pp);
}

// Round 16
// 223.280 us; speedup vs baseline: 2.1224x; 1.0782x over previous
//
#include <hip/hip_runtime.h>
#include <hip/hip_bf16.h>
#include <math.h>

#define NB   1024
#define LL   100
#define DD   256
#define DINN 704
#define VV   32000
#define RR   129
#define KAV  512
#define ROWU 129   // enc LDS row stride in dwords (odd => conflict-free)

typedef float f32x4 __attribute__((ext_vector_type(4)));
typedef short s16x8 __attribute__((ext_vector_type(8)));
typedef unsigned short u16;
typedef unsigned int u32;

__device__ __forceinline__ float sigf(float x) { return 1.0f / (1.0f + __expf(-x)); }

__device__ __forceinline__ u16 f2bf(float f) {
    u32 u = __float_as_uint(f);
    u += 0x7fffu + ((u >> 16) & 1u);
    return (u16)(u >> 16);
}
__device__ __forceinline__ float bf2f(u16 s) {
    return __uint_as_float(((u32)s) << 16);
}

// ---------------------------------------------------------------------------
// K-conv: all fp32->bf16 conversions & transposes + rule_proj (bf16 [r][d]).
//  [0,2000)     prim_emb -> prim_bf          (<129 also rule_proj -> rp_bf)
//  [2000,2352)  W_ih -> wih_bf
//  [2352,2480)  W_hh -> whh_bf
//  [2480,2832)  x -> x_bf
//  [2832,2960)  h0 -> h0_bf
//  [2960,3024)  W_att_vec -> wav_bf          (already [n][k])
//  [3024,3040)  W_attn^T  -> wattnT  (16 tiles 64x64)
//  [3040,3056)  W_ptr^T   -> wptrT   (16 tiles)
//  [3056,3064)  W_prim_proj^T -> wppT (8 tiles)
// ---------------------------------------------------------------------------
__global__ __launch_bounds__(256) void k_conv(
    const float* __restrict__ prim_emb, u16* __restrict__ prim_bf,
    const float* __restrict__ W_ih, u16* __restrict__ wih_bf,
    const float* __restrict__ W_hh, u16* __restrict__ whh_bf,
    const float* __restrict__ x, u16* __restrict__ x_bf,
    const float* __restrict__ h0, u16* __restrict__ h0_bf,
    const float* __restrict__ W_att_vec, u16* __restrict__ wav_bf,
    const float* __restrict__ W_attn, u16* __restrict__ wattnT,
    const float* __restrict__ W_ptr, u16* __restrict__ wptrT,
    const float* __restrict__ W_prim_proj, u16* __restrict__ wppT,
    const float* __restrict__ rule_emb, const float* __restrict__ W_rule_proj,
    u16* __restrict__ rp_bf)
{
    __shared__ float re_s[128];
    __shared__ __align__(16) float tile[64][65];
    const int bx = blockIdx.x, t = threadIdx.x;

    if (bx >= 3024) {                    // LDS-tile transposes
        const float* src; u16* dst; int S, D2, r0, c0;
        if (bx < 3040) { int id = bx - 3024; src = W_attn; dst = wattnT;
                         S = 256; D2 = 256; r0 = (id >> 2) * 64; c0 = (id & 3) * 64; }
        else if (bx < 3056) { int id = bx - 3040; src = W_ptr; dst = wptrT;
                         S = 256; D2 = 256; r0 = (id >> 2) * 64; c0 = (id & 3) * 64; }
        else { int id = bx - 3056; src = W_prim_proj; dst = wppT;
                         S = 128; D2 = 256; r0 = (id >> 1) * 64; c0 = (id & 1) * 64; }
        const int rr = t >> 6, cc = t & 63;
#pragma unroll
        for (int p = 0; p < 16; ++p)
            tile[rr + p * 4][cc] = src[(r0 + rr + p * 4) * S + c0 + cc];
        __syncthreads();
#pragma unroll
        for (int p = 0; p < 16; ++p)
            dst[(c0 + rr + p * 4) * D2 + r0 + cc] = f2bf(tile[cc][rr + p * 4]);
        return;
    }

    const float* src; u16* dst; int off;
    if (bx < 2000)      { src = prim_emb;  dst = prim_bf; off = bx * 2048; }
    else if (bx < 2352) { src = W_ih;      dst = wih_bf;  off = (bx - 2000) * 2048; }
    else if (bx < 2480) { src = W_hh;      dst = whh_bf;  off = (bx - 2352) * 2048; }
    else if (bx < 2832) { src = x;         dst = x_bf;    off = (bx - 2480) * 2048; }
    else if (bx < 2960) { src = h0;        dst = h0_bf;   off = (bx - 2832) * 2048; }
    else                { src = W_att_vec; dst = wav_bf;  off = (bx - 2960) * 2048; }

    if (bx < RR && t < 128) re_s[t] = rule_emb[bx * 128 + t];

    int i = off + t * 8;
    f32x4 a = *reinterpret_cast<const f32x4*>(&src[i]);
    f32x4 b = *reinterpret_cast<const f32x4*>(&src[i + 4]);
    s16x8 r;
    r[0] = (short)f2bf(a[0]); r[1] = (short)f2bf(a[1]);
    r[2] = (short)f2bf(a[2]); r[3] = (short)f2bf(a[3]);
    r[4] = (short)f2bf(b[0]); r[5] = (short)f2bf(b[1]);
    r[6] = (short)f2bf(b[2]); r[7] = (short)f2bf(b[3]);
    *reinterpret_cast<s16x8*>(&dst[i]) = r;

    if (bx < RR) {
        __syncthreads();
        float acc = 0.f;
        const float* __restrict__ wr = &W_rule_proj[t * 128];
#pragma unroll 8
        for (int k = 0; k < 128; k += 4) {
            f32x4 w4 = *reinterpret_cast<const f32x4*>(&wr[k]);
            acc += w4[0] * re_s[k] + w4[1] * re_s[k + 1]
                 + w4[2] * re_s[k + 2] + w4[3] * re_s[k + 3];
        }
        rp_bf[bx * 256 + t] = f2bf(acc);       // [r][d] bf16 (row-major [n][k])
    }
}

// ---------------------------------------------------------------------------
// K1: LSTM via bf16 MFMA (R11-proven) + bf16 h copy for downstream GEMMs.
// ---------------------------------------------------------------------------
__global__ __launch_bounds__(256) void k_lstm(
    const u16* __restrict__ x_bf, const u16* __restrict__ h0_bf,
    const float* __restrict__ c0,
    const u16* __restrict__ wih_bf, const u16* __restrict__ whh_bf,
    const float* __restrict__ b_ih, const float* __restrict__ b_hh,
    float* __restrict__ out_h, float* __restrict__ out_c,
    u16* __restrict__ h_bf)
{
    const int t = threadIdx.x;
    const int lane = t & 63, w = t >> 6;
    const int lm = lane & 15, lq = lane >> 4;
    const int dg = blockIdx.x;
    const int row0 = blockIdx.y * 128 + w * 32;
    f32x4 acc[4][2] = {};

    for (int kt = 0; kt < 22; ++kt) {
        const int ko = kt * 32 + lq * 8;
        s16x8 bfr[4], afr[2];
#pragma unroll
        for (int mg = 0; mg < 4; ++mg)
            bfr[mg] = *reinterpret_cast<const s16x8*>(
                &wih_bf[(mg * 256 + dg * 16 + lm) * DINN + ko]);
#pragma unroll
        for (int ng = 0; ng < 2; ++ng)
            afr[ng] = *reinterpret_cast<const s16x8*>(
                &x_bf[(row0 + ng * 16 + lm) * DINN + ko]);
#pragma unroll
        for (int mg = 0; mg < 4; ++mg)
#pragma unroll
            for (int ng = 0; ng < 2; ++ng)
                acc[mg][ng] = __builtin_amdgcn_mfma_f32_16x16x32_bf16(
                    bfr[mg], afr[ng], acc[mg][ng], 0, 0, 0);
    }
    for (int kt = 0; kt < 8; ++kt) {
        const int ko = kt * 32 + lq * 8;
        s16x8 bfr[4], afr[2];
#pragma unroll
        for (int mg = 0; mg < 4; ++mg)
            bfr[mg] = *reinterpret_cast<const s16x8*>(
                &whh_bf[(mg * 256 + dg * 16 + lm) * DD + ko]);
#pragma unroll
        for (int ng = 0; ng < 2; ++ng)
            afr[ng] = *reinterpret_cast<const s16x8*>(
                &h0_bf[(row0 + ng * 16 + lm) * DD + ko]);
#pragma unroll
        for (int mg = 0; mg < 4; ++mg)
#pragma unroll
            for (int ng = 0; ng < 2; ++ng)
                acc[mg][ng] = __builtin_amdgcn_mfma_f32_16x16x32_bf16(
                    bfr[mg], afr[ng], acc[mg][ng], 0, 0, 0);
    }

    const int dc = dg * 16 + lq * 4;
    f32x4 bi[4];
#pragma unroll
    for (int mg = 0; mg < 4; ++mg) {
        f32x4 a4 = *reinterpret_cast<const f32x4*>(&b_ih[mg * 256 + dc]);
        f32x4 b4 = *reinterpret_cast<const f32x4*>(&b_hh[mg * 256 + dc]);
        bi[mg][0] = a4[0] + b4[0]; bi[mg][1] = a4[1] + b4[1];
        bi[mg][2] = a4[2] + b4[2]; bi[mg][3] = a4[3] + b4[3];
    }
#pragma unroll
    for (int ng = 0; ng < 2; ++ng) {
        const int row = row0 + ng * 16 + lm;
        f32x4 c4 = *reinterpret_cast<const f32x4*>(&c0[row * DD + dc]);
        f32x4 h4, cc4;
#pragma unroll
        for (int r = 0; r < 4; ++r) {
            float iv = acc[0][ng][r] + bi[0][r];
            float fv = acc[1][ng][r] + bi[1][r];
            float gv = acc[2][ng][r] + bi[2][r];
            float ov = acc[3][ng][r] + bi[3][r];
            float cc = sigf(fv) * c4[r] + sigf(iv) * tanhf(gv);
            cc4[r] = cc;
            h4[r] = sigf(ov) * tanhf(cc);
        }
        *reinterpret_cast<f32x4*>(&out_c[row * DD + dc]) = cc4;
        *reinterpret_cast<f32x4*>(&out_h[row * DD + dc]) = h4;
        u32 w0 = (u32)f2bf(h4[0]) | ((u32)f2bf(h4[1]) << 16);
        u32 w1 = (u32)f2bf(h4[2]) | ((u32)f2bf(h4[3]) << 16);
        u32* hb = reinterpret_cast<u32*>(&h_bf[row * DD + dc]);
        hb[0] = w0; hb[1] = w1;
    }
}

// ---------------------------------------------------------------------------
// K-hw: hW = h @ W_attn via bf16 MFMA. grid (2, 8): 128 cols x 128 rows.
// ---------------------------------------------------------------------------
__global__ __launch_bounds__(256) void k_hw(
    const u16* __restrict__ h_bf, const u16* __restrict__ wattnT,
    float* __restrict__ hW)
{
    const int t = threadIdx.x;
    const int lane = t & 63, w = t >> 6;
    const int lm = lane & 15, lq = lane >> 4;
    const int colbase = blockIdx.x * 128 + (w & 1) * 64;
    const int rowbase = blockIdx.y * 128 + (w >> 1) * 64;

    f32x4 acc[4][4] = {};
#pragma unroll
    for (int kg = 0; kg < 8; ++kg) {
        s16x8 pfr[4], afr[4];
#pragma unroll
        for (int mg = 0; mg < 4; ++mg)
            pfr[mg] = *reinterpret_cast<const s16x8*>(
                &wattnT[(colbase + mg * 16 + lm) * 256 + kg * 32 + lq * 8]);
#pragma unroll
        for (int ng = 0; ng < 4; ++ng)
            afr[ng] = *reinterpret_cast<const s16x8*>(
                &h_bf[(rowbase + ng * 16 + lm) * 256 + kg * 32 + lq * 8]);
#pragma unroll
        for (int mg = 0; mg < 4; ++mg)
#pragma unroll
            for (int ng = 0; ng < 4; ++ng)
                acc[mg][ng] = __builtin_amdgcn_mfma_f32_16x16x32_bf16(
                    pfr[mg], afr[ng], acc[mg][ng], 0, 0, 0);
    }
#pragma unroll
    for (int ng = 0; ng < 4; ++ng) {
        const int arow = rowbase + ng * 16 + lm;
#pragma unroll
        for (int mg = 0; mg < 4; ++mg)
            *reinterpret_cast<f32x4*>(&hW[arow * DD + colbase + mg * 16 + lq * 4])
                = acc[mg][ng];
    }
}

// ---------------------------------------------------------------------------
// K-attn2: per-b scores + softmax + ctx (bf16 out). (R11-proven body)
// ---------------------------------------------------------------------------
__global__ __launch_bounds__(256, 2) void k_attn2(
    const float* __restrict__ src_enc, const float* __restrict__ hW,
    u16* __restrict__ ctx_bf)
{
    __shared__ u32 enc_u[LL * ROWU];
    __shared__ __align__(16) float part[4][DD];
    __shared__ __align__(16) float hw_s[DD];
    __shared__ float sc_s[LL];
    __shared__ float al_s[LL];

    const int b = blockIdx.x, t = threadIdx.x;
    const int lane = t & 63, w = t >> 6;
    const float* __restrict__ enc = src_enc + (size_t)b * LL * DD;

    hw_s[t] = hW[b * DD + t];

#pragma unroll
    for (int p = 0; p < 25; ++p) {
        int q = p * 256 + t;
        int l = q >> 6, dq = q & 63;
        f32x4 ev = *reinterpret_cast<const f32x4*>(&enc[l * DD + dq * 4]);
        u32 w0 = (u32)f2bf(ev[0]) | ((u32)f2bf(ev[1]) << 16);
        u32 w1 = (u32)f2bf(ev[2]) | ((u32)f2bf(ev[3]) << 16);
        enc_u[l * ROWU + dq * 2]     = w0;
        enc_u[l * ROWU + dq * 2 + 1] = w1;
    }
    __syncthreads();

    {
        const int sl = ((w >> 1) << 6) + lane;
        float sp = 0.f;
        if (sl < LL) {
            const u32* __restrict__ rp = enc_u + sl * ROWU + ((w & 1) << 6);
            const float* __restrict__ hp = hw_s + ((w & 1) << 7);
#pragma unroll 32
            for (int k = 0; k < 64; ++k) {
                u32 v = rp[k];
                sp = fmaf(bf2f((u16)v),         hp[2 * k],     sp);
                sp = fmaf(bf2f((u16)(v >> 16)), hp[2 * k + 1], sp);
            }
        }
        part[w][lane] = sp;
    }
    __syncthreads();
    if (t < LL) sc_s[t] = part[(t >> 6) << 1][t & 63] + part[((t >> 6) << 1) + 1][t & 63];
    __syncthreads();

    if (w == 0) {
        float v0 = sc_s[lane];
        float v1 = (lane + 64 < LL) ? sc_s[lane + 64] : -1e30f;
        float m = fmaxf(v0, v1);
#pragma unroll
        for (int s = 1; s < 64; s <<= 1) m = fmaxf(m, __shfl_xor(m, s));
        float e0 = __expf(v0 - m);
        float e1 = (lane + 64 < LL) ? __expf(v1 - m) : 0.f;
        float ssum = e0 + e1;
#pragma unroll
        for (int s = 1; s < 64; s <<= 1) ssum += __shfl_xor(ssum, s);
        float inv = 1.f / ssum;
        al_s[lane] = e0 * inv;
        if (lane + 64 < LL) al_s[lane + 64] = e1 * inv;
    }
    __syncthreads();

    {
        const int l0 = w * 25;
        float c0 = 0.f, c1 = 0.f, c2 = 0.f, c3 = 0.f;
#pragma unroll
        for (int li = 0; li < 25; ++li) {
            int l = l0 + li;
            float a = al_s[l];
            u32 v0 = enc_u[l * ROWU + lane * 2];
            u32 v1 = enc_u[l * ROWU + lane * 2 + 1];
            c0 = fmaf(a, bf2f((u16)v0), c0);
            c1 = fmaf(a, bf2f((u16)(v0 >> 16)), c1);
            c2 = fmaf(a, bf2f((u16)v1), c2);
            c3 = fmaf(a, bf2f((u16)(v1 >> 16)), c3);
        }
        f32x4 p; p[0] = c0; p[1] = c1; p[2] = c2; p[3] = c3;
        *reinterpret_cast<f32x4*>(&part[w][lane * 4]) = p;
    }
    __syncthreads();
    ctx_bf[b * DD + t] = f2bf((part[0][t] + part[1][t]) + (part[2][t] + part[3][t]));
}

// ---------------------------------------------------------------------------
// K-att: att = tanh(cat(h,ctx) @ W_att_vec^T) via bf16 MFMA. grid (2,8).
// Outputs o_att fp32 + att2_bf bf16.
// ---------------------------------------------------------------------------
__global__ __launch_bounds__(256) void k_att(
    const u16* __restrict__ h_bf, const u16* __restrict__ ctx_bf,
    const u16* __restrict__ wav_bf,
    float* __restrict__ att_out, u16* __restrict__ att2_bf)
{
    const int t = threadIdx.x;
    const int lane = t & 63, w = t >> 6;
    const int lm = lane & 15, lq = lane >> 4;
    const int colbase = blockIdx.x * 128 + (w & 1) * 64;
    const int rowbase = blockIdx.y * 128 + (w >> 1) * 64;

    f32x4 acc[4][4] = {};
#pragma unroll
    for (int kg = 0; kg < 16; ++kg) {
        const u16* __restrict__ asrc = (kg < 8) ? h_bf : ctx_bf;
        const int ko = (kg & 7) * 32 + lq * 8;
        s16x8 pfr[4], afr[4];
#pragma unroll
        for (int mg = 0; mg < 4; ++mg)
            pfr[mg] = *reinterpret_cast<const s16x8*>(
                &wav_bf[(colbase + mg * 16 + lm) * KAV + kg * 32 + lq * 8]);
#pragma unroll
        for (int ng = 0; ng < 4; ++ng)
            afr[ng] = *reinterpret_cast<const s16x8*>(
                &asrc[(rowbase + ng * 16 + lm) * 256 + ko]);
#pragma unroll
        for (int mg = 0; mg < 4; ++mg)
#pragma unroll
            for (int ng = 0; ng < 4; ++ng)
                acc[mg][ng] = __builtin_amdgcn_mfma_f32_16x16x32_bf16(
                    pfr[mg], afr[ng], acc[mg][ng], 0, 0, 0);
    }
#pragma unroll
    for (int ng = 0; ng < 4; ++ng) {
        const int arow = rowbase + ng * 16 + lm;
#pragma unroll
        for (int mg = 0; mg < 4; ++mg) {
            const int col = colbase + mg * 16 + lq * 4;
            f32x4 v;
#pragma unroll
            for (int r = 0; r < 4; ++r) v[r] = tanhf(acc[mg][ng][r]);
            *reinterpret_cast<f32x4*>(&att_out[arow * DD + col]) = v;
            u32 w0 = (u32)f2bf(v[0]) | ((u32)f2bf(v[1]) << 16);
            u32 w1 = (u32)f2bf(v[2]) | ((u32)f2bf(v[3]) << 16);
            u32* ab = reinterpret_cast<u32*>(&att2_bf[arow * DD + col]);
            ab[0] = w0; ab[1] = w1;
        }
    }
}

// ---------------------------------------------------------------------------
// K-ptrproj: [atW | att_p | rule_logits] via bf16 MFMA. grid (5, 8).
//  x=0,1: atW (wptrT) fp32; x=2: att_p (wppT) bf16; x=3,4: rule (rp_bf) fp32.
// ---------------------------------------------------------------------------
__global__ __launch_bounds__(256) void k_ptrproj(
    const u16* __restrict__ att2_bf, const u16* __restrict__ wptrT,
    const u16* __restrict__ wppT, const u16* __restrict__ rp_bf,
    float* __restrict__ atw, u16* __restrict__ att_bf, float* __restrict__ rl)
{
    const int t = threadIdx.x;
    const int lane = t & 63, w = t >> 6;
    const int lm = lane & 15, lq = lane >> 4;
    const int gx = blockIdx.x;
    const int colbase = gx * 128 + (w & 1) * 64;
    const int rowbase = blockIdx.y * 128 + (w >> 1) * 64;

    const u16* __restrict__ B;
    int noff;
    if (gx < 2)      { B = wptrT; noff = colbase; }
    else if (gx < 3) { B = wppT;  noff = colbase - 256; }
    else             { B = rp_bf; noff = colbase - 384; }

    f32x4 acc[4][4] = {};
#pragma unroll
    for (int kg = 0; kg < 8; ++kg) {
        s16x8 pfr[4], afr[4];
#pragma unroll
        for (int mg = 0; mg < 4; ++mg)
            pfr[mg] = *reinterpret_cast<const s16x8*>(
                &B[(noff + mg * 16 + lm) * 256 + kg * 32 + lq * 8]);
#pragma unroll
        for (int ng = 0; ng < 4; ++ng)
            afr[ng] = *reinterpret_cast<const s16x8*>(
                &att2_bf[(rowbase + ng * 16 + lm) * 256 + kg * 32 + lq * 8]);
#pragma unroll
        for (int mg = 0; mg < 4; ++mg)
#pragma unroll
            for (int ng = 0; ng < 4; ++ng)
                acc[mg][ng] = __builtin_amdgcn_mfma_f32_16x16x32_bf16(
                    pfr[mg], afr[ng], acc[mg][ng], 0, 0, 0);
    }

#pragma unroll
    for (int ng = 0; ng < 4; ++ng) {
        const int arow = rowbase + ng * 16 + lm;
        if (gx < 2) {
#pragma unroll
            for (int mg = 0; mg < 4; ++mg)
                *reinterpret_cast<f32x4*>(&atw[arow * DD + colbase + mg * 16 + lq * 4])
                    = acc[mg][ng];
        } else if (gx < 3) {
#pragma unroll
            for (int mg = 0; mg < 4; ++mg) {
                const int col = noff + mg * 16 + lq * 4;
                u32 w0 = (u32)f2bf(acc[mg][ng][0]) | ((u32)f2bf(acc[mg][ng][1]) << 16);
                u32 w1 = (u32)f2bf(acc[mg][ng][2]) | ((u32)f2bf(acc[mg][ng][3]) << 16);
                u32* ab = reinterpret_cast<u32*>(&att_bf[arow * 128 + col]);
                ab[0] = w0; ab[1] = w1;
            }
        } else {
#pragma unroll
            for (int mg = 0; mg < 4; ++mg)
#pragma unroll
                for (int r = 0; r < 4; ++r) {
                    int rc = noff + mg * 16 + lq * 4 + r;
                    if (rc < RR) rl[arow * 132 + rc] = acc[mg][ng][r];
                }
        }
    }
}

// ---------------------------------------------------------------------------
// K-fin: rule log-softmax + gate. (R11-proven)
// ---------------------------------------------------------------------------
__global__ __launch_bounds__(256) void k_fin(
    const float* __restrict__ rl, const float* __restrict__ att,
    const float* __restrict__ w_gen, const float* __restrict__ b_gen,
    float* __restrict__ log_p_rule, float* __restrict__ gate0_ws,
    float* __restrict__ gate1_ws)
{
    const int w = threadIdx.x >> 6, lane = threadIdx.x & 63;
    const int b = blockIdx.x * 4 + w;

    float v0 = rl[b * 132 + lane];
    float v1 = rl[b * 132 + 64 + lane];
    float v2 = (lane == 0) ? rl[b * 132 + 128] : -1e30f;
    float m = fmaxf(fmaxf(v0, v1), v2);
#pragma unroll
    for (int s = 1; s < 64; s <<= 1) m = fmaxf(m, __shfl_xor(m, s));
    float ssum = __expf(v0 - m) + __expf(v1 - m) + ((lane == 0) ? __expf(v2 - m) : 0.f);
#pragma unroll
    for (int s = 1; s < 64; s <<= 1) ssum += __shfl_xor(ssum, s);
    float ls = m + logf(ssum);
    log_p_rule[b * RR + lane] = v0 - ls;
    log_p_rule[b * RR + 64 + lane] = v1 - ls;
    if (lane == 0) log_p_rule[b * RR + 128] = v2 - ls;

    f32x4 a4 = *reinterpret_cast<const f32x4*>(&att[b * DD + lane * 4]);
    f32x4 g0 = *reinterpret_cast<const f32x4*>(&w_gen[lane * 4]);
    f32x4 g1 = *reinterpret_cast<const f32x4*>(&w_gen[DD + lane * 4]);
    float p0 = a4[0] * g0[0] + a4[1] * g0[1] + a4[2] * g0[2] + a4[3] * g0[3];
    float p1 = a4[0] * g1[0] + a4[1] * g1[1] + a4[2] * g1[2] + a4[3] * g1[3];
#pragma unroll
    for (int s = 1; s < 64; s <<= 1) { p0 += __shfl_xor(p0, s); p1 += __shfl_xor(p1, s); }
    if (lane == 0) {
        float ga = p0 + b_gen[0], gb = p1 + b_gen[1];
        float gm = fmaxf(ga, gb);
        float ea = __expf(ga - gm), eb = __expf(gb - gm);
        gate0_ws[b] = ea / (ea + eb);
        gate1_ws[b] = eb / (ea + eb);
    }
}

// ---------------------------------------------------------------------------
// K-ptr2: pointer scores, wave-per-l coalesced + gated copy mass. (R11)
// ---------------------------------------------------------------------------
__global__ __launch_bounds__(256) void k_ptr2(
    const float* __restrict__ src_enc, const float* __restrict__ atw,
    const float* __restrict__ gate1_ws, float* __restrict__ copy_mass)
{
    __shared__ float sc_s[LL];
    const int b = blockIdx.x, t = threadIdx.x;
    const int lane = t & 63, w = t >> 6;
    const float* __restrict__ enc = src_enc + (size_t)b * LL * DD;
    f32x4 aw4 = *reinterpret_cast<const f32x4*>(&atw[b * DD + lane * 4]);

    for (int l = w; l < LL; l += 4) {
        f32x4 ev = *reinterpret_cast<const f32x4*>(&enc[l * DD + lane * 4]);
        float pr = aw4[0] * ev[0] + aw4[1] * ev[1] + aw4[2] * ev[2] + aw4[3] * ev[3];
#pragma unroll
        for (int m = 1; m < 64; m <<= 1) pr += __shfl_xor(pr, m);
        if (lane == 0) sc_s[l] = pr;
    }
    __syncthreads();
    if (w == 0) {
        float gate1 = gate1_ws[b];
        float v0 = sc_s[lane];
        float v1 = (lane + 64 < LL) ? sc_s[lane + 64] : -1e30f;
        float m = fmaxf(v0, v1);
#pragma unroll
        for (int s = 1; s < 64; s <<= 1) m = fmaxf(m, __shfl_xor(m, s));
        float ee0 = __expf(v0 - m);
        float ee1 = (lane + 64 < LL) ? __expf(v1 - m) : 0.f;
        float ssum = ee0 + ee1;
#pragma unroll
        for (int s = 1; s < 64; s <<= 1) ssum += __shfl_xor(ssum, s);
        float inv = 1.f / ssum;
        copy_mass[b * LL + lane] = gate1 * ee0 * inv;
        if (lane + 64 < LL) copy_mass[b * LL + lane + 64] = gate1 * ee1 * inv;
    }
}

// ---------------------------------------------------------------------------
// K7: logits pass (bf16 MFMA). PASS0: sumexp stats; PASS1: p_prim write.
// ---------------------------------------------------------------------------
template <int PASS>
__global__ __launch_bounds__(256) void k_prim(
    const u16* __restrict__ att_bf, const u16* __restrict__ prim_bf,
    const float* __restrict__ coef, float* __restrict__ stats, float* __restrict__ p_prim)
{
    const int t = threadIdx.x;
    const int lane = t & 63, w = t >> 6;
    const int lm = lane & 15, lq = lane >> 4;
    const int colbase = blockIdx.x * 128 + (w & 1) * 64;
    const int chunk = colbase >> 6;
    const int rowblk = blockIdx.y * 256;

    s16x8 pfr[4][4];
#pragma unroll
    for (int kg = 0; kg < 4; ++kg)
#pragma unroll
        for (int mg = 0; mg < 4; ++mg)
            pfr[kg][mg] = *reinterpret_cast<const s16x8*>(
                &prim_bf[(size_t)(colbase + mg * 16 + lm) * 128 + kg * 32 + lq * 8]);

    for (int it = 0; it < 2; ++it) {
        const int rowbase = rowblk + it * 128 + (w >> 1) * 64;
        f32x4 acc[4][4] = {};
#pragma unroll
        for (int kg = 0; kg < 4; ++kg) {
            s16x8 afr[4];
#pragma unroll
            for (int ng = 0; ng < 4; ++ng)
                afr[ng] = *reinterpret_cast<const s16x8*>(
                    &att_bf[(rowbase + ng * 16 + lm) * 128 + kg * 32 + lq * 8]);
#pragma unroll
            for (int mg = 0; mg < 4; ++mg)
#pragma unroll
                for (int ng = 0; ng < 4; ++ng)
                    acc[mg][ng] = __builtin_amdgcn_mfma_f32_16x16x32_bf16(
                        pfr[kg][mg], afr[ng], acc[mg][ng], 0, 0, 0);
        }
        if (PASS == 0) {
#pragma unroll
            for (int ng = 0; ng < 4; ++ng) {
                float se = 0.f;
#pragma unroll
                for (int mg = 0; mg < 4; ++mg)
                    se += __expf(acc[mg][ng][0]) + __expf(acc[mg][ng][1])
                        + __expf(acc[mg][ng][2]) + __expf(acc[mg][ng][3]);
                se += __shfl_xor(se, 16);
                se += __shfl_xor(se, 32);
                if (lq == 0)
                    stats[chunk * NB + rowbase + ng * 16 + lm] = se;
            }
        } else {
#pragma unroll
            for (int ng = 0; ng < 4; ++ng) {
                const int arow = rowbase + ng * 16 + lm;
                const float cf = coef[arow];
                float* __restrict__ dst = &p_prim[(size_t)arow * VV + colbase + lq * 4];
#pragma unroll
                for (int mg = 0; mg < 4; ++mg) {
                    f32x4 v;
                    v[0] = cf * __expf(acc[mg][ng][0]);
                    v[1] = cf * __expf(acc[mg][ng][1]);
                    v[2] = cf * __expf(acc[mg][ng][2]);
                    v[3] = cf * __expf(acc[mg][ng][3]);
                    *reinterpret_cast<f32x4*>(&dst[mg * 16]) = v;
                }
            }
        }
    }
}

// ---------------------------------------------------------------------------
// K8: combine chunk-major sumexp -> coef = gate0/total (coalesced).
// ---------------------------------------------------------------------------
__global__ __launch_bounds__(256) void k_combine(
    const float* __restrict__ stats, const float* __restrict__ gate0_ws,
    float* __restrict__ coef)
{
    const int row = blockIdx.x * 256 + threadIdx.x;
    float s0 = 0.f, s1 = 0.f, s2 = 0.f, s3 = 0.f;
    for (int c = 0; c < 500; c += 4) {
        s0 += stats[(c)     * NB + row];
        s1 += stats[(c + 1) * NB + row];
        s2 += stats[(c + 2) * NB + row];
        s3 += stats[(c + 3) * NB + row];
    }
    coef[row] = gate0_ws[row] / ((s0 + s1) + (s2 + s3));
}

// ---------------------------------------------------------------------------
// K9: scatter copy mass into p_prim rows (copy_mass pre-gated)
// ---------------------------------------------------------------------------
__global__ __launch_bounds__(256) void k_scatter(
    const int* __restrict__ tok, const float* __restrict__ copy_mass,
    float* __restrict__ p_prim)
{
    int i = blockIdx.x * 256 + threadIdx.x;
    if (i >= NB * LL) return;
    int b = i / LL;
    atomicAdd(&p_prim[(size_t)b * VV + tok[i]], copy_mass[i]);
}

// ---------------------------------------------------------------------------
extern "C" void kernel_launch(void* const* d_in, const int* in_sizes, int n_in,
                              void* d_out, int out_size, void* d_ws, size_t ws_size,
                              hipStream_t stream)
{
    const float* x         = (const float*)d_in[0];
    const float* h0        = (const float*)d_in[1];
    const float* c0        = (const float*)d_in[2];
    const float* src_enc   = (const float*)d_in[3];
    const int*   tok       = (const int*)  d_in[4];
    const float* W_ih      = (const float*)d_in[5];
    const float* b_ih      = (const float*)d_in[6];
    const float* W_hh      = (const float*)d_in[7];
    const float* b_hh      = (const float*)d_in[8];
    const float* W_attn    = (const float*)d_in[9];
    const float* W_att_vec = (const float*)d_in[10];
    const float* W_ptr     = (const float*)d_in[11];
    const float* rule_emb  = (const float*)d_in[12];
    const float* W_rule_pr = (const float*)d_in[13];
    const float* prim_emb  = (const float*)d_in[14];
    const float* W_prim_pr = (const float*)d_in[15];
    const float* w_gen     = (const float*)d_in[16];
    const float* b_gen     = (const float*)d_in[17];

    float* out    = (float*)d_out;
    float* o_logp = out;                               // [1024,129]
    float* o_pp   = out + 1024 * 129;                  // [1024,32000]
    float* o_h    = o_pp + (size_t)1024 * 32000;       // [1024,256]
    float* o_c    = o_h + 1024 * 256;                  // [1024,256]
    float* o_att  = o_c + 1024 * 256;                  // [1024,256]

    float* wsf      = (float*)d_ws;
    float* ws_rl    = wsf;                     // 135168 (rule logits 1024x132)
    float* ws_gate0 = ws_rl    + 135168;       // 1024
    float* ws_gate1 = ws_gate0 + 1024;         // 1024
    float* ws_cm    = ws_gate1 + 1024;         // 102400
    float* ws_coef  = ws_cm    + 102400;       // 1024
    float* ws_hw    = ws_coef  + 1024;         // 262144
    float* ws_atw   = ws_hw    + 262144;       // 262144
    float* ws_stats = ws_atw   + 262144;       // 512000
    u16*   ub       = (u16*)(ws_stats + 512000);
    u16*   ws_attbf = ub;                      // 131,072
    u16*   ws_primbf= ws_attbf + 131072;       // 4,096,000
    u16*   ws_xb    = ws_primbf + 4096000;     // 720,896
    u16*   ws_h0b   = ws_xb    + 720896;       // 262,144
    u16*   ws_wihb  = ws_h0b   + 262144;       // 720,896
    u16*   ws_whhb  = ws_wihb  + 720896;       // 262,144
    u16*   ws_hbf   = ws_whhb  + 262144;       // 262,144
    u16*   ws_ctxbf = ws_hbf   + 262144;       // 262,144
    u16*   ws_att2  = ws_ctxbf + 262144;       // 262,144
    u16*   ws_wavb  = ws_att2  + 262144;       // 131,072
    u16*   ws_wattnT= ws_wavb  + 131072;       // 65,536
    u16*   ws_wptrT = ws_wattnT+ 65536;        // 65,536
    u16*   ws_wppT  = ws_wptrT + 65536;        // 32,768
    u16*   ws_rpb   = ws_wppT  + 32768;        // 65,536 (256x256; rows >=129 unused)
    // total ~ 19.3 MB

    k_conv<<<dim3(3064), 256, 0, stream>>>(prim_emb, ws_primbf, W_ih, ws_wihb,
                                           W_hh, ws_whhb, x, ws_xb, h0, ws_h0b,
                                           W_att_vec, ws_wavb, W_attn, ws_wattnT,
                                           W_ptr, ws_wptrT, W_prim_pr, ws_wppT,
                                           rule_emb, W_rule_pr, ws_rpb);
    k_lstm<<<dim3(16, 8), 256, 0, stream>>>(ws_xb, ws_h0b, c0, ws_wihb, ws_whhb,
                                            b_ih, b_hh, o_h, o_c, ws_hbf);
    k_hw<<<dim3(2, 8), 256, 0, stream>>>(ws_hbf, ws_wattnT, ws_hw);
    k_attn2<<<dim3(1024), 256, 0, stream>>>(src_enc, ws_hw, ws_ctxbf);
    k_att<<<dim3(2, 8), 256, 0, stream>>>(ws_hbf, ws_ctxbf, ws_wavb, o_att, ws_att2);
    k_ptrproj<<<dim3(5, 8), 256, 0, stream>>>(ws_att2, ws_wptrT, ws_wppT, ws_rpb,
                                              ws_atw, ws_attbf, ws_rl);
    k_fin<<<dim3(256), 256, 0, stream>>>(ws_rl, o_att, w_gen, b_gen,
                                         o_logp, ws_gate0, ws_gate1);
    k_ptr2<<<dim3(1024), 256, 0, stream>>>(src_enc, ws_atw, ws_gate1, ws_cm);
    k_prim<0><<<dim3(250, 4), 256, 0, stream>>>(ws_attbf, ws_primbf, nullptr, ws_stats, nullptr);
    k_combine<<<dim3(4), 256, 0, stream>>>(ws_stats, ws_gate0, ws_coef);
    k_prim<1><<<dim3(250, 4), 256, 0, stream>>>(ws_attbf, ws_primbf, ws_coef, nullptr, o_pp);
    k_scatter<<<dim3(400), 256, 0, stream>>>(tok, ws_cm, o_pp);
}